// Round 2
// baseline (381.957 us; speedup 1.0000x reference)
//
#include <hip/hip_runtime.h>
#include <hip/hip_bf16.h>
#include <stdint.h>
#include <stddef.h>

// Inputs/outputs are fp32 (reference dtype). We cast inputs to bf16 in the
// workspace, run all GEMMs as bf16-MFMA / fp32-accumulate, and write fp32 out.
typedef __bf16 bf16_t;
typedef __bf16 bf16x4 __attribute__((ext_vector_type(4)));
typedef __bf16 bf16x8 __attribute__((ext_vector_type(8)));
typedef float  floatx4 __attribute__((ext_vector_type(4)));

#define TM 128
#define TN 128
#define TK 32

// Vectorized fp32 -> bf16 cast. n must be a multiple of 4 (all our tensors
// have n % 1024 == 0).
__global__ void cast_f32_bf16(const float* __restrict__ src,
                              bf16_t* __restrict__ dst, int n) {
    int i = (blockIdx.x * blockDim.x + threadIdx.x) * 4;
    if (i < n) {
        float4 f = *(const float4*)(src + i);
        bf16x4 o;
        o.x = (bf16_t)f.x; o.y = (bf16_t)f.y;
        o.z = (bf16_t)f.z; o.w = (bf16_t)f.w;
        *(bf16x4*)(dst + i) = o;
    }
}

// C[M,N] = scale * (A[M,K] @ B[N,K]^T) + bias;  bias fp32.
// bias_mode: 0 = none, 1 = bias[col], 2 = bias[row]
// Requires M%128==0, N%128==0, K%32==0. m97-style: 128x128 tile, 4 waves
// (2x2), each wave 64x64 via 4x4 of 16x16x32 bf16 MFMA, global_load_lds
// width=16 staging into unpadded row-major LDS tiles.
template <typename OutT>
__global__ __launch_bounds__(256, 2) void gemm_bt(
    const bf16_t* __restrict__ A,
    const bf16_t* __restrict__ B,
    OutT* __restrict__ C,
    const float* __restrict__ bias,
    int M, int N, int K, float scale, int bias_mode)
{
    __shared__ __align__(16) bf16_t As[TM * TK];
    __shared__ __align__(16) bf16_t Bs[TN * TK];

    const int tid  = threadIdx.x;      // 0..255
    const int lane = tid & 63;
    const int wave = tid >> 6;         // 0..3
    const int wm   = wave >> 1;        // 0..1
    const int wn   = wave & 1;         // 0..1

    const int bm = blockIdx.y * TM;
    const int bn = blockIdx.x * TN;

    floatx4 acc[4][4] = {};            // 64 accum VGPRs

    // Staging: tile = 128 rows x 32 cols bf16 = 8 KiB = 512 x 16B chunks.
    // chunk c: row = c>>2, col-byte = (c&3)*16. LDS dest = c*16 bytes ==
    // wave-uniform base + lane*16 (global_load_lds constraint; no padding).
    const int c0 = tid;
    const int c1 = tid + 256;
    const int r0 = c0 >> 2, o0 = (c0 & 3) * 8;
    const int r1 = c1 >> 2, o1 = (c1 & 3) * 8;

    // MFMA 16x16x32 bf16 fragment coords (verified layout):
    // A frag: A[m = lane&15][k = (lane>>4)*8 + j]  (8 contiguous k -> b128)
    const int fr = lane & 15;
    const int fk = (lane >> 4) * 8;

    for (int kt = 0; kt < K; kt += TK) {
        const bf16_t* gA0 = A + (size_t)(bm + r0) * K + kt + o0;
        const bf16_t* gA1 = A + (size_t)(bm + r1) * K + kt + o1;
        const bf16_t* gB0 = B + (size_t)(bn + r0) * K + kt + o0;
        const bf16_t* gB1 = B + (size_t)(bn + r1) * K + kt + o1;
        __builtin_amdgcn_global_load_lds(
            (const __attribute__((address_space(1))) void*)gA0,
            (__attribute__((address_space(3))) void*)&As[c0 * 8], 16, 0, 0);
        __builtin_amdgcn_global_load_lds(
            (const __attribute__((address_space(1))) void*)gA1,
            (__attribute__((address_space(3))) void*)&As[c1 * 8], 16, 0, 0);
        __builtin_amdgcn_global_load_lds(
            (const __attribute__((address_space(1))) void*)gB0,
            (__attribute__((address_space(3))) void*)&Bs[c0 * 8], 16, 0, 0);
        __builtin_amdgcn_global_load_lds(
            (const __attribute__((address_space(1))) void*)gB1,
            (__attribute__((address_space(3))) void*)&Bs[c1 * 8], 16, 0, 0);
        __syncthreads();

        bf16x8 af[4], bg[4];
        #pragma unroll
        for (int i = 0; i < 4; ++i) {
            af[i] = *(const bf16x8*)&As[(wm * 64 + i * 16 + fr) * TK + fk];
            bg[i] = *(const bf16x8*)&Bs[(wn * 64 + i * 16 + fr) * TK + fk];
        }
        #pragma unroll
        for (int i = 0; i < 4; ++i) {
            #pragma unroll
            for (int j = 0; j < 4; ++j) {
                acc[i][j] = __builtin_amdgcn_mfma_f32_16x16x32_bf16(
                    af[i], bg[j], acc[i][j], 0, 0, 0);
            }
        }
        __syncthreads();
    }

    // Epilogue. C/D layout (verified): col = lane&15, row = (lane>>4)*4 + reg.
    const int rq = (lane >> 4) * 4;
    #pragma unroll
    for (int i = 0; i < 4; ++i) {
        #pragma unroll
        for (int j = 0; j < 4; ++j) {
            const int col = bn + wn * 64 + j * 16 + fr;
            #pragma unroll
            for (int r = 0; r < 4; ++r) {
                const int row = bm + wm * 64 + i * 16 + rq + r;
                float v = acc[i][j][r] * scale;
                if (bias_mode == 1)      v += bias[col];
                else if (bias_mode == 2) v += bias[row];
                C[(size_t)row * N + col] = (OutT)v;
            }
        }
    }
}

extern "C" void kernel_launch(void* const* d_in, const int* in_sizes, int n_in,
                              void* d_out, int out_size, void* d_ws, size_t ws_size,
                              hipStream_t stream) {
    const int SEQ = 8192;   // N in the reference
    const int H   = 1024;

    const float* x  = (const float*)d_in[0];
    const float* Wq = (const float*)d_in[1];
    const float* bq = (const float*)d_in[2];
    const float* Wk = (const float*)d_in[3];
    const float* bk = (const float*)d_in[4];
    const float* Wv = (const float*)d_in[5];
    const float* bv = (const float*)d_in[6];
    float* out = (float*)d_out;

    // Workspace layout (bf16 buffers, peak 56 MiB):
    //   [ 0Mi,16Mi)  xb  [SEQ][H]
    //   [16Mi,18Mi)  Wqb [H][H]
    //   [18Mi,20Mi)  Wkb [H][H]
    //   [20Mi,22Mi)  Wvb [H][H]
    //   [22Mi,38Mi)  KT  [H][SEQ], reused as Q [SEQ][H] after stage 3
    //   [38Mi,54Mi)  VT  [H][SEQ]
    //   [54Mi,56Mi)  Tt  [H][H]
    const size_t MI = 1024 * 1024;
    char* ws = (char*)d_ws;
    bf16_t* xb  = (bf16_t*)(ws);
    bf16_t* Wqb = (bf16_t*)(ws + 16 * MI);
    bf16_t* Wkb = (bf16_t*)(ws + 18 * MI);
    bf16_t* Wvb = (bf16_t*)(ws + 20 * MI);
    bf16_t* KT  = (bf16_t*)(ws + 22 * MI);
    bf16_t* VT  = (bf16_t*)(ws + 38 * MI);
    bf16_t* Tt  = (bf16_t*)(ws + 54 * MI);
    bf16_t* Q   = KT;   // overwrites KT after stage 3 (stream-ordered)

    dim3 blk(256);
    const float inv_sqrt_h = 1.0f / 32.0f;   // 1/sqrt(1024)

    // 0) Cast fp32 inputs -> bf16 workspace copies.
    {
        const int nx = SEQ * H, nw = H * H;
        cast_f32_bf16<<<dim3(nx / 4 / 256), blk, 0, stream>>>(x,  xb,  nx);
        cast_f32_bf16<<<dim3(nw / 4 / 256), blk, 0, stream>>>(Wq, Wqb, nw);
        cast_f32_bf16<<<dim3(nw / 4 / 256), blk, 0, stream>>>(Wk, Wkb, nw);
        cast_f32_bf16<<<dim3(nw / 4 / 256), blk, 0, stream>>>(Wv, Wvb, nw);
    }

    // 1) KT[h][n] = sum_k Wk[h][k] x[n][k] + bk[h]   == K^T with bias
    gemm_bt<bf16_t><<<dim3(SEQ / TN, H / TM), blk, 0, stream>>>(
        Wkb, xb, KT, bk, H, SEQ, H, 1.0f, 2);
    // 2) VT[h][n] = sum_k Wv[h][k] x[n][k] + bv[h]   == V^T with bias
    gemm_bt<bf16_t><<<dim3(SEQ / TN, H / TM), blk, 0, stream>>>(
        Wvb, xb, VT, bv, H, SEQ, H, 1.0f, 2);
    // 3) Tt[j][i] = (1/32) * sum_n VT[j][n] KT[i][n] == ((K^T V)/32)^T
    gemm_bt<bf16_t><<<dim3(H / TN, H / TM), blk, 0, stream>>>(
        VT, KT, Tt, nullptr, H, H, SEQ, inv_sqrt_h, 0);
    // 4) Q[m][i] = sum_k x[m][k] Wq[i][k] + bq[i]
    gemm_bt<bf16_t><<<dim3(H / TN, SEQ / TM), blk, 0, stream>>>(
        xb, Wqb, Q, bq, SEQ, H, H, 1.0f, 1);
    // 5) out[m][j] = sum_i Q[m][i] Tt[j][i]  == (Q K^T / 32) V  (fp32 out)
    gemm_bt<float><<<dim3(H / TN, SEQ / TM), blk, 0, stream>>>(
        Q, Tt, out, nullptr, SEQ, H, H, 1.0f, 0);
}

// Round 3
// 274.336 us; speedup vs baseline: 1.3923x; 1.3923x over previous
//
#include <hip/hip_runtime.h>
#include <hip/hip_bf16.h>
#include <stdint.h>
#include <stddef.h>

// Inputs/outputs are fp32 (reference dtype). We cast inputs to bf16 in the
// workspace, run all GEMMs as bf16-MFMA / fp32-accumulate, and write fp32 out.
typedef __bf16 bf16_t;
typedef __bf16 bf16x4 __attribute__((ext_vector_type(4)));
typedef __bf16 bf16x8 __attribute__((ext_vector_type(8)));
typedef float  floatx4 __attribute__((ext_vector_type(4)));

#define TM 128
#define TN 128
#define TK 32

// Vectorized fp32 -> bf16 cast. n must be a multiple of 1024.
__global__ void cast_f32_bf16(const float* __restrict__ src,
                              bf16_t* __restrict__ dst, int n) {
    int i = (blockIdx.x * blockDim.x + threadIdx.x) * 4;
    if (i < n) {
        float4 f = *(const float4*)(src + i);
        bf16x4 o;
        o.x = (bf16_t)f.x; o.y = (bf16_t)f.y;
        o.z = (bf16_t)f.z; o.w = (bf16_t)f.w;
        *(bf16x4*)(dst + i) = o;
    }
}

// Cast three H*H fp32 weights -> bf16 in one launch. Grid covers 3*nw/4.
__global__ void cast3_f32_bf16(const float* __restrict__ s0, bf16_t* __restrict__ d0,
                               const float* __restrict__ s1, bf16_t* __restrict__ d1,
                               const float* __restrict__ s2, bf16_t* __restrict__ d2,
                               int nw) {
    int i = (blockIdx.x * blockDim.x + threadIdx.x) * 4;
    const float* s; bf16_t* d; int off;
    if (i < nw)            { s = s0; d = d0; off = i; }
    else if (i < 2 * nw)   { s = s1; d = d1; off = i - nw; }
    else                   { s = s2; d = d2; off = i - 2 * nw; }
    float4 f = *(const float4*)(s + off);
    bf16x4 o;
    o.x = (bf16_t)f.x; o.y = (bf16_t)f.y;
    o.z = (bf16_t)f.z; o.w = (bf16_t)f.w;
    *(bf16x4*)(d + off) = o;
}

// Sum nsplit fp32 partial slabs of n elems, scale, cast to bf16.
__global__ void reduce_splitk(const float* __restrict__ part,
                              bf16_t* __restrict__ dst, int n, int nsplit,
                              float scale) {
    int i = (blockIdx.x * blockDim.x + threadIdx.x) * 4;
    if (i < n) {
        float4 s = *(const float4*)(part + i);
        for (int z = 1; z < nsplit; ++z) {
            float4 p = *(const float4*)(part + (size_t)z * n + i);
            s.x += p.x; s.y += p.y; s.z += p.z; s.w += p.w;
        }
        bf16x4 o;
        o.x = (bf16_t)(s.x * scale); o.y = (bf16_t)(s.y * scale);
        o.z = (bf16_t)(s.z * scale); o.w = (bf16_t)(s.w * scale);
        *(bf16x4*)(dst + i) = o;
    }
}

// C[z][M,N] = scale * (A[M, k0:k0+kChunk] @ B[N, k0:k0+kChunk]^T) + bias,
// where z = blockIdx.z, k0 = z*kChunk, and C is offset by z*M*N per split.
// Non-split launches: gridDim.z = 1, kChunk = K.
// bias_mode: 0 = none, 1 = bias[col], 2 = bias[row];  bias fp32.
// Requires M%128==0, N%128==0, kChunk%32==0. m97-style: 128x128 tile,
// 4 waves (2x2), each wave 64x64 via 4x4 of 16x16x32 bf16 MFMA,
// global_load_lds width=16 into unpadded row-major LDS tiles.
template <typename OutT>
__global__ __launch_bounds__(256, 2) void gemm_bt(
    const bf16_t* __restrict__ A,
    const bf16_t* __restrict__ B,
    OutT* __restrict__ C,
    const float* __restrict__ bias,
    int M, int N, int K, int kChunk, float scale, int bias_mode)
{
    __shared__ __align__(16) bf16_t As[TM * TK];
    __shared__ __align__(16) bf16_t Bs[TN * TK];

    const int tid  = threadIdx.x;      // 0..255
    const int lane = tid & 63;
    const int wave = tid >> 6;         // 0..3
    const int wm   = wave >> 1;        // 0..1
    const int wn   = wave & 1;         // 0..1

    const int bm = blockIdx.y * TM;
    const int bn = blockIdx.x * TN;
    const int k0 = blockIdx.z * kChunk;
    C += (size_t)blockIdx.z * M * N;

    floatx4 acc[4][4] = {};            // 64 accum VGPRs

    // Staging: tile = 128 rows x 32 cols bf16 = 8 KiB = 512 x 16B chunks.
    // chunk c: row = c>>2, elem-off = (c&3)*8. LDS dest = c*16 bytes ==
    // wave-uniform base + lane*16 (global_load_lds constraint; no padding).
    const int c0 = tid;
    const int c1 = tid + 256;
    const int r0 = c0 >> 2, o0 = (c0 & 3) * 8;
    const int r1 = c1 >> 2, o1 = (c1 & 3) * 8;

    // MFMA 16x16x32 bf16 fragment coords (verified layout):
    // A frag: A[m = lane&15][k = (lane>>4)*8 + j]  (8 contiguous k -> b128)
    const int fr = lane & 15;
    const int fk = (lane >> 4) * 8;

    for (int kt = k0; kt < k0 + kChunk; kt += TK) {
        const bf16_t* gA0 = A + (size_t)(bm + r0) * K + kt + o0;
        const bf16_t* gA1 = A + (size_t)(bm + r1) * K + kt + o1;
        const bf16_t* gB0 = B + (size_t)(bn + r0) * K + kt + o0;
        const bf16_t* gB1 = B + (size_t)(bn + r1) * K + kt + o1;
        __builtin_amdgcn_global_load_lds(
            (const __attribute__((address_space(1))) void*)gA0,
            (__attribute__((address_space(3))) void*)&As[c0 * 8], 16, 0, 0);
        __builtin_amdgcn_global_load_lds(
            (const __attribute__((address_space(1))) void*)gA1,
            (__attribute__((address_space(3))) void*)&As[c1 * 8], 16, 0, 0);
        __builtin_amdgcn_global_load_lds(
            (const __attribute__((address_space(1))) void*)gB0,
            (__attribute__((address_space(3))) void*)&Bs[c0 * 8], 16, 0, 0);
        __builtin_amdgcn_global_load_lds(
            (const __attribute__((address_space(1))) void*)gB1,
            (__attribute__((address_space(3))) void*)&Bs[c1 * 8], 16, 0, 0);
        __syncthreads();

        bf16x8 af[4], bg[4];
        #pragma unroll
        for (int i = 0; i < 4; ++i) {
            af[i] = *(const bf16x8*)&As[(wm * 64 + i * 16 + fr) * TK + fk];
            bg[i] = *(const bf16x8*)&Bs[(wn * 64 + i * 16 + fr) * TK + fk];
        }
        #pragma unroll
        for (int i = 0; i < 4; ++i) {
            #pragma unroll
            for (int j = 0; j < 4; ++j) {
                acc[i][j] = __builtin_amdgcn_mfma_f32_16x16x32_bf16(
                    af[i], bg[j], acc[i][j], 0, 0, 0);
            }
        }
        __syncthreads();
    }

    // Epilogue. C/D layout (verified): col = lane&15, row = (lane>>4)*4 + reg.
    const int rq = (lane >> 4) * 4;
    #pragma unroll
    for (int i = 0; i < 4; ++i) {
        #pragma unroll
        for (int j = 0; j < 4; ++j) {
            const int col = bn + wn * 64 + j * 16 + fr;
            #pragma unroll
            for (int r = 0; r < 4; ++r) {
                const int row = bm + wm * 64 + i * 16 + rq + r;
                float v = acc[i][j][r] * scale;
                if (bias_mode == 1)      v += bias[col];
                else if (bias_mode == 2) v += bias[row];
                C[(size_t)row * N + col] = (OutT)v;
            }
        }
    }
}

extern "C" void kernel_launch(void* const* d_in, const int* in_sizes, int n_in,
                              void* d_out, int out_size, void* d_ws, size_t ws_size,
                              hipStream_t stream) {
    const int SEQ = 8192;   // N in the reference
    const int H   = 1024;
    const int NSPLIT = 8;   // split-K factor for stage 3

    const float* x  = (const float*)d_in[0];
    const float* Wq = (const float*)d_in[1];
    const float* bq = (const float*)d_in[2];
    const float* Wk = (const float*)d_in[3];
    const float* bk = (const float*)d_in[4];
    const float* Wv = (const float*)d_in[5];
    const float* bv = (const float*)d_in[6];
    float* out = (float*)d_out;

    // Workspace layout (bf16 buffers, peak 56 MiB):
    //   [ 0Mi,16Mi)  xb  [SEQ][H]
    //   [16Mi,18Mi)  Wqb [H][H]
    //   [18Mi,20Mi)  Wkb [H][H]
    //   [20Mi,22Mi)  Wvb [H][H]
    //   [22Mi,38Mi)  KT  [H][SEQ], reused as Q [SEQ][H] after stage 3
    //   [38Mi,54Mi)  VT  [H][SEQ]
    //   [54Mi,56Mi)  Tt  [H][H]
    // Stage-3 fp32 split-K partials [NSPLIT][H][H] = 32 MiB live in d_out
    // (unused until stage 5; stream-ordered).
    const size_t MI = 1024 * 1024;
    char* ws = (char*)d_ws;
    bf16_t* xb  = (bf16_t*)(ws);
    bf16_t* Wqb = (bf16_t*)(ws + 16 * MI);
    bf16_t* Wkb = (bf16_t*)(ws + 18 * MI);
    bf16_t* Wvb = (bf16_t*)(ws + 20 * MI);
    bf16_t* KT  = (bf16_t*)(ws + 22 * MI);
    bf16_t* VT  = (bf16_t*)(ws + 38 * MI);
    bf16_t* Tt  = (bf16_t*)(ws + 54 * MI);
    bf16_t* Q   = KT;   // overwrites KT after stage 3 (stream-ordered)

    dim3 blk(256);
    const float inv_sqrt_h = 1.0f / 32.0f;   // 1/sqrt(1024)

    // 0) Cast fp32 inputs -> bf16 workspace copies.
    {
        const int nx = SEQ * H, nw = H * H;
        cast_f32_bf16<<<dim3(nx / 4 / 256), blk, 0, stream>>>(x, xb, nx);
        cast3_f32_bf16<<<dim3(3 * nw / 4 / 256), blk, 0, stream>>>(
            Wq, Wqb, Wk, Wkb, Wv, Wvb, nw);
    }

    // 1) KT[h][n] = sum_k Wk[h][k] x[n][k] + bk[h]   == K^T with bias
    gemm_bt<bf16_t><<<dim3(SEQ / TN, H / TM), blk, 0, stream>>>(
        Wkb, xb, KT, bk, H, SEQ, H, H, 1.0f, 2);
    // 2) VT[h][n] = sum_k Wv[h][k] x[n][k] + bv[h]   == V^T with bias
    gemm_bt<bf16_t><<<dim3(SEQ / TN, H / TM), blk, 0, stream>>>(
        Wvb, xb, VT, bv, H, SEQ, H, H, 1.0f, 2);
    // 3) split-K: partial[z][j][i] = sum_{n in chunk z} VT[j][n] KT[i][n]
    gemm_bt<float><<<dim3(H / TN, H / TM, NSPLIT), blk, 0, stream>>>(
        VT, KT, out, nullptr, H, H, SEQ, SEQ / NSPLIT, 1.0f, 0);
    //    Tt[j][i] = (1/32) * sum_z partial[z][j][i]
    reduce_splitk<<<dim3(H * H / 4 / 256), blk, 0, stream>>>(
        out, Tt, H * H, NSPLIT, inv_sqrt_h);
    // 4) Q[m][i] = sum_k x[m][k] Wq[i][k] + bq[i]
    gemm_bt<bf16_t><<<dim3(H / TN, SEQ / TM), blk, 0, stream>>>(
        xb, Wqb, Q, bq, SEQ, H, H, H, 1.0f, 1);
    // 5) out[m][j] = sum_i Q[m][i] Tt[j][i]  == (Q K^T / 32) V  (fp32 out)
    gemm_bt<float><<<dim3(H / TN, SEQ / TM), blk, 0, stream>>>(
        Q, Tt, out, nullptr, SEQ, H, H, H, 1.0f, 0);
}

// Round 4
// 257.535 us; speedup vs baseline: 1.4831x; 1.0652x over previous
//
#include <hip/hip_runtime.h>
#include <hip/hip_bf16.h>
#include <stdint.h>
#include <stddef.h>

// SelfAttention without softmax is bilinear => factor through the Gram matrix:
//   out = x*U + 1*c,  U = Wq^T T /32,  c = bq T /32,
//   T = K^T V = Wk G Wv^T + (Wk s)(x)bv + bk(x)(Wv s) + N bk(x)bv,
//   G = x^T x  (HxH),  s = colsum(x).
// Only two SEQ-sized GEMMs remain (G and the final x*U); the rest is H^3.
typedef __bf16 bf16_t;
typedef __bf16 bf16x4 __attribute__((ext_vector_type(4)));
typedef __bf16 bf16x8 __attribute__((ext_vector_type(8)));
typedef float  floatx4 __attribute__((ext_vector_type(4)));

#define TM 128
#define TN 128
#define TK 32

// Fused over x [SEQ][H]: straight cast -> xb, transpose cast -> xbT [H][SEQ],
// column sums -> s (fp32, must be zeroed first). Tile 64x64, block 256.
__global__ void prep_x(const float* __restrict__ x, bf16_t* __restrict__ xb,
                       bf16_t* __restrict__ xbT, float* __restrict__ s,
                       int SEQ, int H) {
    __shared__ bf16_t tile[64][72];
    __shared__ float csum[64];
    const int t = threadIdx.x;
    const int n0 = blockIdx.x * 64, k0 = blockIdx.y * 64;
    const int c4 = t & 15;          // float4 index within a 64-col row
    const int rbase = t >> 4;       // 0..15
    float acc0 = 0.f, acc1 = 0.f, acc2 = 0.f, acc3 = 0.f;
    if (t < 64) csum[t] = 0.f;
    #pragma unroll
    for (int p = 0; p < 4; ++p) {
        const int r = rbase + 16 * p;
        const size_t gidx = (size_t)(n0 + r) * H + k0 + c4 * 4;
        float4 f = *(const float4*)(x + gidx);
        bf16x4 o;
        o.x = (bf16_t)f.x; o.y = (bf16_t)f.y;
        o.z = (bf16_t)f.z; o.w = (bf16_t)f.w;
        *(bf16x4*)(xb + gidx) = o;
        *(bf16x4*)&tile[r][c4 * 4] = o;
        acc0 += f.x; acc1 += f.y; acc2 += f.z; acc3 += f.w;
    }
    __syncthreads();
    atomicAdd(&csum[c4 * 4 + 0], acc0);
    atomicAdd(&csum[c4 * 4 + 1], acc1);
    atomicAdd(&csum[c4 * 4 + 2], acc2);
    atomicAdd(&csum[c4 * 4 + 3], acc3);
    // transpose writes: 64 rows of xbT, 64 bf16 each = 512 bf16x8 chunks
    #pragma unroll
    for (int p = 0; p < 2; ++p) {
        const int q = t + 256 * p;
        const int kk = q >> 3;
        const int n8 = (q & 7) * 8;
        bf16x8 v;
        #pragma unroll
        for (int u = 0; u < 8; ++u) v[u] = tile[n8 + u][kk];
        *(bf16x8*)(xbT + (size_t)(k0 + kk) * SEQ + n0 + n8) = v;
    }
    __syncthreads();
    if (t < 64) atomicAdd(s + k0 + t, csum[t]);
}

// Transpose-cast fp32 src[R][C] -> bf16 dst[C][R]. Tiles 64x64, block 256,
// grid (R/64, C/64).
__global__ void tcast(const float* __restrict__ src, bf16_t* __restrict__ dst,
                      int R, int C) {
    __shared__ bf16_t tile[64][72];
    const int t = threadIdx.x;
    const int r0 = blockIdx.x * 64, c0 = blockIdx.y * 64;
    const int c4 = t & 15;
    const int rbase = t >> 4;
    #pragma unroll
    for (int p = 0; p < 4; ++p) {
        const int r = rbase + 16 * p;
        float4 f = *(const float4*)(src + (size_t)(r0 + r) * C + c0 + c4 * 4);
        bf16x4 o;
        o.x = (bf16_t)f.x; o.y = (bf16_t)f.y;
        o.z = (bf16_t)f.z; o.w = (bf16_t)f.w;
        *(bf16x4*)&tile[r][c4 * 4] = o;
    }
    __syncthreads();
    #pragma unroll
    for (int p = 0; p < 2; ++p) {
        const int q = t + 256 * p;
        const int cc = q >> 3;
        const int r8 = (q & 7) * 8;
        bf16x8 v;
        #pragma unroll
        for (int u = 0; u < 8; ++u) v[u] = tile[r8 + u][cc];
        *(bf16x8*)(dst + (size_t)(c0 + cc) * R + r0 + r8) = v;
    }
}

// Vectorized fp32 -> bf16 cast. n multiple of 1024.
__global__ void cast_f32_bf16(const float* __restrict__ src,
                              bf16_t* __restrict__ dst, int n) {
    int i = (blockIdx.x * blockDim.x + threadIdx.x) * 4;
    if (i < n) {
        float4 f = *(const float4*)(src + i);
        bf16x4 o;
        o.x = (bf16_t)f.x; o.y = (bf16_t)f.y;
        o.z = (bf16_t)f.z; o.w = (bf16_t)f.w;
        *(bf16x4*)(dst + i) = o;
    }
}

// y[row] = scale * sum_a M[row][a] * v[a].  M bf16 [rows][ncols], v fp32.
// Block 256 = 4 waves, one wave per row; grid rows/4.
__global__ void matvec_bf16(const bf16_t* __restrict__ M,
                            const float* __restrict__ v,
                            float* __restrict__ y, int ncols, float scale) {
    const int lane = threadIdx.x & 63;
    const int row = blockIdx.x * 4 + (threadIdx.x >> 6);
    const bf16_t* mp = M + (size_t)row * ncols;
    float acc = 0.f;
    for (int a = lane * 8; a < ncols; a += 64 * 8) {
        bf16x8 m8 = *(const bf16x8*)(mp + a);
        #pragma unroll
        for (int u = 0; u < 8; ++u) acc += (float)m8[u] * v[a + u];
    }
    #pragma unroll
    for (int off = 32; off; off >>= 1) acc += __shfl_down(acc, off);
    if (lane == 0) y[row] = acc * scale;
}

// Sum nsplit fp32 partial slabs of n elems, scale, cast to bf16.
__global__ void reduce_splitk(const float* __restrict__ part,
                              bf16_t* __restrict__ dst, int n, int nsplit,
                              float scale) {
    int i = (blockIdx.x * blockDim.x + threadIdx.x) * 4;
    if (i < n) {
        float4 ssum = *(const float4*)(part + i);
        for (int z = 1; z < nsplit; ++z) {
            float4 p = *(const float4*)(part + (size_t)z * n + i);
            ssum.x += p.x; ssum.y += p.y; ssum.z += p.z; ssum.w += p.w;
        }
        bf16x4 o;
        o.x = (bf16_t)(ssum.x * scale); o.y = (bf16_t)(ssum.y * scale);
        o.z = (bf16_t)(ssum.z * scale); o.w = (bf16_t)(ssum.w * scale);
        *(bf16x4*)(dst + i) = o;
    }
}

// Split-K reduce for Tt [H][H] plus rank-1 bias terms:
//   Tt[j][i] = sum_z part + bv[j]*kv1[i] + wvs[j]*bk[i] + cN*bv[j]*bk[i]
__global__ void reduce_rank1(const float* __restrict__ part,
                             bf16_t* __restrict__ dst, int n, int nsplit,
                             const float* __restrict__ bv,
                             const float* __restrict__ kv1,
                             const float* __restrict__ wvs,
                             const float* __restrict__ bk,
                             float cN, int Hdim) {
    int i = (blockIdx.x * blockDim.x + threadIdx.x) * 4;
    if (i < n) {
        float4 ssum = *(const float4*)(part + i);
        for (int z = 1; z < nsplit; ++z) {
            float4 p = *(const float4*)(part + (size_t)z * n + i);
            ssum.x += p.x; ssum.y += p.y; ssum.z += p.z; ssum.w += p.w;
        }
        const int j = i / Hdim, ii = i % Hdim;
        const float bvj = bv[j], wvsj = wvs[j];
        float4 kv = *(const float4*)(kv1 + ii);
        float4 bkv = *(const float4*)(bk + ii);
        bf16x4 o;
        o.x = (bf16_t)(ssum.x + bvj * kv.x + wvsj * bkv.x + cN * bvj * bkv.x);
        o.y = (bf16_t)(ssum.y + bvj * kv.y + wvsj * bkv.y + cN * bvj * bkv.y);
        o.z = (bf16_t)(ssum.z + bvj * kv.z + wvsj * bkv.z + cN * bvj * bkv.z);
        o.w = (bf16_t)(ssum.w + bvj * kv.w + wvsj * bkv.w + cN * bvj * bkv.w);
        *(bf16x4*)(dst + i) = o;
    }
}

// C[z][M,N] = scale * (A[M, k0:k0+kChunk] @ B[N, k0:k0+kChunk]^T) + bias,
// z = blockIdx.z, k0 = z*kChunk, C offset by z*M*N. Non-split: gridDim.z=1,
// kChunk=K. bias_mode: 0 none, 1 bias[col], 2 bias[row]; bias fp32.
// M%128==0, N%128==0, kChunk%32==0. m97-style 128x128 tile, 4 waves.
template <typename OutT>
__global__ __launch_bounds__(256, 2) void gemm_bt(
    const bf16_t* __restrict__ A,
    const bf16_t* __restrict__ B,
    OutT* __restrict__ C,
    const float* __restrict__ bias,
    int M, int N, int K, int kChunk, float scale, int bias_mode)
{
    __shared__ __align__(16) bf16_t As[TM * TK];
    __shared__ __align__(16) bf16_t Bs[TN * TK];

    const int tid  = threadIdx.x;
    const int lane = tid & 63;
    const int wave = tid >> 6;
    const int wm   = wave >> 1;
    const int wn   = wave & 1;

    const int bm = blockIdx.y * TM;
    const int bn = blockIdx.x * TN;
    const int k0 = blockIdx.z * kChunk;
    C += (size_t)blockIdx.z * M * N;

    floatx4 acc[4][4] = {};

    const int c0 = tid;
    const int c1 = tid + 256;
    const int r0 = c0 >> 2, o0 = (c0 & 3) * 8;
    const int r1 = c1 >> 2, o1 = (c1 & 3) * 8;

    const int fr = lane & 15;
    const int fk = (lane >> 4) * 8;

    for (int kt = k0; kt < k0 + kChunk; kt += TK) {
        const bf16_t* gA0 = A + (size_t)(bm + r0) * K + kt + o0;
        const bf16_t* gA1 = A + (size_t)(bm + r1) * K + kt + o1;
        const bf16_t* gB0 = B + (size_t)(bn + r0) * K + kt + o0;
        const bf16_t* gB1 = B + (size_t)(bn + r1) * K + kt + o1;
        __builtin_amdgcn_global_load_lds(
            (const __attribute__((address_space(1))) void*)gA0,
            (__attribute__((address_space(3))) void*)&As[c0 * 8], 16, 0, 0);
        __builtin_amdgcn_global_load_lds(
            (const __attribute__((address_space(1))) void*)gA1,
            (__attribute__((address_space(3))) void*)&As[c1 * 8], 16, 0, 0);
        __builtin_amdgcn_global_load_lds(
            (const __attribute__((address_space(1))) void*)gB0,
            (__attribute__((address_space(3))) void*)&Bs[c0 * 8], 16, 0, 0);
        __builtin_amdgcn_global_load_lds(
            (const __attribute__((address_space(1))) void*)gB1,
            (__attribute__((address_space(3))) void*)&Bs[c1 * 8], 16, 0, 0);
        __syncthreads();

        bf16x8 af[4], bg[4];
        #pragma unroll
        for (int i = 0; i < 4; ++i) {
            af[i] = *(const bf16x8*)&As[(wm * 64 + i * 16 + fr) * TK + fk];
            bg[i] = *(const bf16x8*)&Bs[(wn * 64 + i * 16 + fr) * TK + fk];
        }
        #pragma unroll
        for (int i = 0; i < 4; ++i) {
            #pragma unroll
            for (int j = 0; j < 4; ++j) {
                acc[i][j] = __builtin_amdgcn_mfma_f32_16x16x32_bf16(
                    af[i], bg[j], acc[i][j], 0, 0, 0);
            }
        }
        __syncthreads();
    }

    const int rq = (lane >> 4) * 4;
    #pragma unroll
    for (int i = 0; i < 4; ++i) {
        #pragma unroll
        for (int j = 0; j < 4; ++j) {
            const int col = bn + wn * 64 + j * 16 + fr;
            #pragma unroll
            for (int r = 0; r < 4; ++r) {
                const int row = bm + wm * 64 + i * 16 + rq + r;
                float v = acc[i][j][r] * scale;
                if (bias_mode == 1)      v += bias[col];
                else if (bias_mode == 2) v += bias[row];
                C[(size_t)row * N + col] = (OutT)v;
            }
        }
    }
}

extern "C" void kernel_launch(void* const* d_in, const int* in_sizes, int n_in,
                              void* d_out, int out_size, void* d_ws, size_t ws_size,
                              hipStream_t stream) {
    const int SEQ = 8192;
    const int H   = 1024;

    const float* x  = (const float*)d_in[0];
    const float* Wq = (const float*)d_in[1];
    const float* bq = (const float*)d_in[2];
    const float* Wk = (const float*)d_in[3];
    const float* bk = (const float*)d_in[4];
    const float* Wv = (const float*)d_in[5];
    const float* bv = (const float*)d_in[6];
    float* out = (float*)d_out;

    // Workspace (46 MiB + vectors):
    //   [ 0,16)Mi xb [SEQ][H]      [16,32)Mi xbT [H][SEQ]
    //   [32,34)Mi Wkb  [34,36)Mi Wvb  [36,38)Mi WqT (bf16 [k][i])
    //   [38,40)Mi Gb   [40,42)Mi S1b  [42,44)Mi Ttb  [44,46)Mi Utb
    //   46Mi+: s, kv1, wvs, cvec (fp32 H each)
    // Split-K fp32 partials live in d_out (32 MiB; unused until final GEMM).
    const size_t MI = 1024 * 1024;
    char* ws = (char*)d_ws;
    bf16_t* xb   = (bf16_t*)(ws);
    bf16_t* xbT  = (bf16_t*)(ws + 16 * MI);
    bf16_t* Wkb  = (bf16_t*)(ws + 32 * MI);
    bf16_t* Wvb  = (bf16_t*)(ws + 34 * MI);
    bf16_t* WqTb = (bf16_t*)(ws + 36 * MI);
    bf16_t* Gb   = (bf16_t*)(ws + 38 * MI);
    bf16_t* S1b  = (bf16_t*)(ws + 40 * MI);
    bf16_t* Ttb  = (bf16_t*)(ws + 42 * MI);
    bf16_t* Utb  = (bf16_t*)(ws + 44 * MI);
    float*  svec = (float*)(ws + 46 * MI);
    float*  kv1  = svec + 1024;
    float*  wvs  = svec + 2048;
    float*  cvec = svec + 3072;
    float*  part = out;     // split-K partial slabs

    dim3 blk(256);
    const float inv32 = 1.0f / 32.0f;   // 1/sqrt(1024)
    const int nHH = H * H;

    // 0) x -> xb, xbT, s (colsum).  Weights: Wk,Wv straight; Wq transposed.
    hipMemsetAsync(svec, 0, H * sizeof(float), stream);
    prep_x<<<dim3(SEQ / 64, H / 64), blk, 0, stream>>>(x, xb, xbT, svec, SEQ, H);
    cast_f32_bf16<<<dim3(nHH / 1024), blk, 0, stream>>>(Wk, Wkb, nHH);
    cast_f32_bf16<<<dim3(nHH / 1024), blk, 0, stream>>>(Wv, Wvb, nHH);
    tcast<<<dim3(H / 64, H / 64), blk, 0, stream>>>(Wq, WqTb, H, H);

    // 1) G = x^T x  (split-K 8)
    gemm_bt<float><<<dim3(H / TN, H / TM, 8), blk, 0, stream>>>(
        xbT, xbT, part, nullptr, H, H, SEQ, SEQ / 8, 1.0f, 0);
    reduce_splitk<<<dim3(nHH / 1024), blk, 0, stream>>>(part, Gb, nHH, 8, 1.0f);

    // 2) kv1 = Wk s, wvs = Wv s
    matvec_bf16<<<dim3(H / 4), blk, 0, stream>>>(Wkb, svec, kv1, H, 1.0f);
    matvec_bf16<<<dim3(H / 4), blk, 0, stream>>>(Wvb, svec, wvs, H, 1.0f);

    // 3) S1[j][a] = sum_b Wv[j][b] G[a][b]  (G symmetric; split-K 4)
    gemm_bt<float><<<dim3(H / TN, H / TM, 4), blk, 0, stream>>>(
        Wvb, Gb, part, nullptr, H, H, H, H / 4, 1.0f, 0);
    reduce_splitk<<<dim3(nHH / 1024), blk, 0, stream>>>(part, S1b, nHH, 4, 1.0f);

    // 4) Tt[j][i] = sum_a S1[j][a] Wk[i][a] + rank-1 bias terms
    gemm_bt<float><<<dim3(H / TN, H / TM, 4), blk, 0, stream>>>(
        S1b, Wkb, part, nullptr, H, H, H, H / 4, 1.0f, 0);
    reduce_rank1<<<dim3(nHH / 1024), blk, 0, stream>>>(
        part, Ttb, nHH, 4, bv, kv1, wvs, bk, (float)SEQ, H);

    // 5) c = Tt bq / 32 ;  Ut[j][k] = (1/32) sum_i Tt[j][i] Wq[i][k]
    matvec_bf16<<<dim3(H / 4), blk, 0, stream>>>(Ttb, bq, cvec, H, inv32);
    gemm_bt<float><<<dim3(H / TN, H / TM, 4), blk, 0, stream>>>(
        Ttb, WqTb, part, nullptr, H, H, H, H / 4, 1.0f, 0);
    reduce_splitk<<<dim3(nHH / 1024), blk, 0, stream>>>(part, Utb, nHH, 4, inv32);

    // 6) out[m][j] = sum_k xb[m][k] Ut[j][k] + c[j]   (fp32 out)
    gemm_bt<float><<<dim3(H / TN, SEQ / TM), blk, 0, stream>>>(
        xb, Utb, out, cvec, SEQ, H, H, H, 1.0f, 1);
}

// Round 5
// 245.984 us; speedup vs baseline: 1.5528x; 1.0470x over previous
//
#include <hip/hip_runtime.h>
#include <hip/hip_bf16.h>
#include <stdint.h>
#include <stddef.h>

// out = x*U + 1*c,  U = Wq^T T /32,  c = bq T /32,
// T = K^T V = Wk G Wv^T + (Wk s)(x)bv + bk(x)(Wv s) + N bk(x)bv,
// G = x^T x (HxH), s = colsum(x). Two SEQ-sized GEMMs (G, x*U); rest is H^3.
typedef __bf16 bf16_t;
typedef __bf16 bf16x4 __attribute__((ext_vector_type(4)));
typedef __bf16 bf16x8 __attribute__((ext_vector_type(8)));
typedef float  floatx4 __attribute__((ext_vector_type(4)));

#define TK 32

// Fused over x [SEQ][H]: cast -> xb, transpose cast -> xbT [H][SEQ],
// column sums -> s (fp32, zeroed first). Tile 64x64, block 256.
__global__ void prep_x(const float* __restrict__ x, bf16_t* __restrict__ xb,
                       bf16_t* __restrict__ xbT, float* __restrict__ s,
                       int SEQ, int H) {
    __shared__ bf16_t tile[64][72];
    __shared__ float csum[64];
    const int t = threadIdx.x;
    const int n0 = blockIdx.x * 64, k0 = blockIdx.y * 64;
    const int c4 = t & 15;
    const int rbase = t >> 4;
    float a0 = 0.f, a1 = 0.f, a2 = 0.f, a3 = 0.f;
    if (t < 64) csum[t] = 0.f;
    #pragma unroll
    for (int p = 0; p < 4; ++p) {
        const int r = rbase + 16 * p;
        const size_t gidx = (size_t)(n0 + r) * H + k0 + c4 * 4;
        float4 f = *(const float4*)(x + gidx);
        bf16x4 o;
        o.x = (bf16_t)f.x; o.y = (bf16_t)f.y;
        o.z = (bf16_t)f.z; o.w = (bf16_t)f.w;
        *(bf16x4*)(xb + gidx) = o;
        *(bf16x4*)&tile[r][c4 * 4] = o;
        a0 += f.x; a1 += f.y; a2 += f.z; a3 += f.w;
    }
    __syncthreads();
    atomicAdd(&csum[c4 * 4 + 0], a0);
    atomicAdd(&csum[c4 * 4 + 1], a1);
    atomicAdd(&csum[c4 * 4 + 2], a2);
    atomicAdd(&csum[c4 * 4 + 3], a3);
    #pragma unroll
    for (int p = 0; p < 2; ++p) {
        const int q = t + 256 * p;
        const int kk = q >> 3;
        const int n8 = (q & 7) * 8;
        bf16x8 v;
        #pragma unroll
        for (int u = 0; u < 8; ++u) v[u] = tile[n8 + u][kk];
        *(bf16x8*)(xbT + (size_t)(k0 + kk) * SEQ + n0 + n8) = v;
    }
    __syncthreads();
    if (t < 64) atomicAdd(s + k0 + t, csum[t]);
}

// Fused weight prep: blocks [0,1024) cast Wk, [1024,2048) cast Wv,
// [2048,2304) transpose-cast Wq 64x64 tiles (H=1024 fixed).
__global__ void prep_w(const float* __restrict__ Wk, bf16_t* __restrict__ Wkb,
                       const float* __restrict__ Wv, bf16_t* __restrict__ Wvb,
                       const float* __restrict__ Wq, bf16_t* __restrict__ WqTb) {
    __shared__ bf16_t tile[64][72];
    const int b = blockIdx.x;
    const int t = threadIdx.x;
    if (b < 2048) {
        const float* s = (b < 1024) ? Wk : Wv;
        bf16_t* d = (b < 1024) ? Wkb : Wvb;
        const int base = (b & 1023) * 1024 + t * 4;
        float4 f = *(const float4*)(s + base);
        bf16x4 o;
        o.x = (bf16_t)f.x; o.y = (bf16_t)f.y;
        o.z = (bf16_t)f.z; o.w = (bf16_t)f.w;
        *(bf16x4*)(d + base) = o;
    } else {
        const int bb = b - 2048;
        const int r0 = (bb & 15) * 64, c0 = (bb >> 4) * 64;
        const int c4 = t & 15;
        const int rbase = t >> 4;
        #pragma unroll
        for (int p = 0; p < 4; ++p) {
            const int r = rbase + 16 * p;
            float4 f = *(const float4*)(Wq + (size_t)(r0 + r) * 1024 + c0 + c4 * 4);
            bf16x4 o;
            o.x = (bf16_t)f.x; o.y = (bf16_t)f.y;
            o.z = (bf16_t)f.z; o.w = (bf16_t)f.w;
            *(bf16x4*)&tile[r][c4 * 4] = o;
        }
        __syncthreads();
        #pragma unroll
        for (int p = 0; p < 2; ++p) {
            const int q = t + 256 * p;
            const int cc = q >> 3;
            const int r8 = (q & 7) * 8;
            bf16x8 v;
            #pragma unroll
            for (int u = 0; u < 8; ++u) v[u] = tile[r8 + u][cc];
            *(bf16x8*)(WqTb + (size_t)(c0 + cc) * 1024 + r0 + r8) = v;
        }
    }
}

// Two matvecs in one launch: y0 = M0 v (rows 0..1023), y1 = M1 v.
// One wave per row; block 256 = 4 waves; grid 512.
__global__ void matvec2(const bf16_t* __restrict__ M0,
                        const bf16_t* __restrict__ M1,
                        const float* __restrict__ v,
                        float* __restrict__ y0, float* __restrict__ y1,
                        int ncols) {
    const int lane = threadIdx.x & 63;
    const int row = blockIdx.x * 4 + (threadIdx.x >> 6);
    const bf16_t* mp;
    float* y;
    if (row < 1024) { mp = M0 + (size_t)row * ncols;          y = y0 + row; }
    else            { mp = M1 + (size_t)(row - 1024) * ncols; y = y1 + row - 1024; }
    float acc = 0.f;
    for (int a = lane * 8; a < ncols; a += 512) {
        bf16x8 m8 = *(const bf16x8*)(mp + a);
        #pragma unroll
        for (int u = 0; u < 8; ++u) acc += (float)m8[u] * v[a + u];
    }
    #pragma unroll
    for (int off = 32; off; off >>= 1) acc += __shfl_down(acc, off);
    if (lane == 0) *y = acc;
}

// y[row] = scale * sum_a M[row][a] * v[a]
__global__ void matvec_bf16(const bf16_t* __restrict__ M,
                            const float* __restrict__ v,
                            float* __restrict__ y, int ncols, float scale) {
    const int lane = threadIdx.x & 63;
    const int row = blockIdx.x * 4 + (threadIdx.x >> 6);
    const bf16_t* mp = M + (size_t)row * ncols;
    float acc = 0.f;
    for (int a = lane * 8; a < ncols; a += 512) {
        bf16x8 m8 = *(const bf16x8*)(mp + a);
        #pragma unroll
        for (int u = 0; u < 8; ++u) acc += (float)m8[u] * v[a + u];
    }
    #pragma unroll
    for (int off = 32; off; off >>= 1) acc += __shfl_down(acc, off);
    if (lane == 0) y[row] = acc * scale;
}

// Sum nsplit fp32 partial slabs of n elems, scale, cast to bf16.
__global__ void reduce_splitk(const float* __restrict__ part,
                              bf16_t* __restrict__ dst, int n, int nsplit,
                              float scale) {
    int i = (blockIdx.x * blockDim.x + threadIdx.x) * 4;
    if (i < n) {
        float4 ssum = *(const float4*)(part + i);
        for (int z = 1; z < nsplit; ++z) {
            float4 p = *(const float4*)(part + (size_t)z * n + i);
            ssum.x += p.x; ssum.y += p.y; ssum.z += p.z; ssum.w += p.w;
        }
        bf16x4 o;
        o.x = (bf16_t)(ssum.x * scale); o.y = (bf16_t)(ssum.y * scale);
        o.z = (bf16_t)(ssum.z * scale); o.w = (bf16_t)(ssum.w * scale);
        *(bf16x4*)(dst + i) = o;
    }
}

// Split-K reduce plus rank-1 bias terms:
//   Tt[j][i] = sum_z part + bv[j]*kv1[i] + wvs[j]*bk[i] + cN*bv[j]*bk[i]
__global__ void reduce_rank1(const float* __restrict__ part,
                             bf16_t* __restrict__ dst, int n, int nsplit,
                             const float* __restrict__ bv,
                             const float* __restrict__ kv1,
                             const float* __restrict__ wvs,
                             const float* __restrict__ bk,
                             float cN, int Hdim) {
    int i = (blockIdx.x * blockDim.x + threadIdx.x) * 4;
    if (i < n) {
        float4 ssum = *(const float4*)(part + i);
        for (int z = 1; z < nsplit; ++z) {
            float4 p = *(const float4*)(part + (size_t)z * n + i);
            ssum.x += p.x; ssum.y += p.y; ssum.z += p.z; ssum.w += p.w;
        }
        const int j = i / Hdim, ii = i % Hdim;
        const float bvj = bv[j], wvsj = wvs[j];
        float4 kv = *(const float4*)(kv1 + ii);
        float4 bkv = *(const float4*)(bk + ii);
        bf16x4 o;
        o.x = (bf16_t)(ssum.x + bvj * kv.x + wvsj * bkv.x + cN * bvj * bkv.x);
        o.y = (bf16_t)(ssum.y + bvj * kv.y + wvsj * bkv.y + cN * bvj * bkv.y);
        o.z = (bf16_t)(ssum.z + bvj * kv.z + wvsj * bkv.z + cN * bvj * bkv.z);
        o.w = (bf16_t)(ssum.w + bvj * kv.w + wvsj * bkv.w + cN * bvj * bkv.w);
        *(bf16x4*)(dst + i) = o;
    }
}

// C[z][M,N] = scale*(A[M, k0:k0+kChunk] @ B[N, k0:k0+kChunk]^T) + bias.
// Tile TMp x TNp, 4 waves (2x2), per-wave (TMp/2)x(TNp/2) via 16x16x32 bf16
// MFMA; global_load_lds width-16 into unpadded row-major LDS tiles.
// z = blockIdx.z, k0 = z*kChunk, C offset z*M*N. bias_mode: 0/1(col)/2(row).
template <int TMp, int TNp, typename OutT>
__global__ __launch_bounds__(256, 2) void gemm_bt(
    const bf16_t* __restrict__ A,
    const bf16_t* __restrict__ B,
    OutT* __restrict__ C,
    const float* __restrict__ bias,
    int M, int N, int K, int kChunk, float scale, int bias_mode)
{
    __shared__ __align__(16) bf16_t As[TMp * TK];
    __shared__ __align__(16) bf16_t Bs[TNp * TK];
    constexpr int MF = TMp / 32;   // 16-row frags per wave (m)
    constexpr int NF = TNp / 32;   // 16-col frags per wave (n)
    constexpr int nA = TMp / 64;   // A 16B-chunks per thread
    constexpr int nB = TNp / 64;

    const int tid  = threadIdx.x;
    const int lane = tid & 63;
    const int wave = tid >> 6;
    const int wm   = wave >> 1;
    const int wn   = wave & 1;

    const int bm = blockIdx.y * TMp;
    const int bn = blockIdx.x * TNp;
    const int k0 = blockIdx.z * kChunk;
    C += (size_t)blockIdx.z * M * N;

    floatx4 acc[MF][NF] = {};

    const int fr = lane & 15;
    const int fk = (lane >> 4) * 8;

    for (int kt = k0; kt < k0 + kChunk; kt += TK) {
        #pragma unroll
        for (int p = 0; p < nA; ++p) {
            const int c = tid + 256 * p;
            const int r = c >> 2, o = (c & 3) * 8;
            __builtin_amdgcn_global_load_lds(
                (const __attribute__((address_space(1))) void*)
                    (A + (size_t)(bm + r) * K + kt + o),
                (__attribute__((address_space(3))) void*)&As[c * 8], 16, 0, 0);
        }
        #pragma unroll
        for (int p = 0; p < nB; ++p) {
            const int c = tid + 256 * p;
            const int r = c >> 2, o = (c & 3) * 8;
            __builtin_amdgcn_global_load_lds(
                (const __attribute__((address_space(1))) void*)
                    (B + (size_t)(bn + r) * K + kt + o),
                (__attribute__((address_space(3))) void*)&Bs[c * 8], 16, 0, 0);
        }
        __syncthreads();

        bf16x8 af[MF], bg[NF];
        #pragma unroll
        for (int i = 0; i < MF; ++i)
            af[i] = *(const bf16x8*)&As[(wm * (TMp / 2) + i * 16 + fr) * TK + fk];
        #pragma unroll
        for (int j = 0; j < NF; ++j)
            bg[j] = *(const bf16x8*)&Bs[(wn * (TNp / 2) + j * 16 + fr) * TK + fk];
        #pragma unroll
        for (int i = 0; i < MF; ++i) {
            #pragma unroll
            for (int j = 0; j < NF; ++j) {
                acc[i][j] = __builtin_amdgcn_mfma_f32_16x16x32_bf16(
                    af[i], bg[j], acc[i][j], 0, 0, 0);
            }
        }
        __syncthreads();
    }

    // C/D layout (verified): col = lane&15, row = (lane>>4)*4 + reg.
    const int rq = (lane >> 4) * 4;
    #pragma unroll
    for (int i = 0; i < MF; ++i) {
        #pragma unroll
        for (int j = 0; j < NF; ++j) {
            const int col = bn + wn * (TNp / 2) + j * 16 + fr;
            #pragma unroll
            for (int r = 0; r < 4; ++r) {
                const int row = bm + wm * (TMp / 2) + i * 16 + rq + r;
                float v = acc[i][j][r] * scale;
                if (bias_mode == 1)      v += bias[col];
                else if (bias_mode == 2) v += bias[row];
                C[(size_t)row * N + col] = (OutT)v;
            }
        }
    }
}

extern "C" void kernel_launch(void* const* d_in, const int* in_sizes, int n_in,
                              void* d_out, int out_size, void* d_ws, size_t ws_size,
                              hipStream_t stream) {
    const int SEQ = 8192;
    const int H   = 1024;

    const float* x  = (const float*)d_in[0];
    const float* Wq = (const float*)d_in[1];
    const float* bq = (const float*)d_in[2];
    const float* Wk = (const float*)d_in[3];
    const float* bk = (const float*)d_in[4];
    const float* Wv = (const float*)d_in[5];
    const float* bv = (const float*)d_in[6];
    float* out = (float*)d_out;

    // Workspace (ws_size ~256 MiB observed; we use 46 MiB + vectors):
    //   [ 0,16)Mi xb   [16,32)Mi xbT
    //   [32,34)Mi Wkb  [34,36)Mi Wvb  [36,38)Mi WqTb
    //   [38,40)Mi Gb   [40,42)Mi S1b  [42,44)Mi Ttb  [44,46)Mi Utb
    //   46Mi+: svec,kv1,wvs,cvec (fp32 H each)
    // Split-K fp32 partials live in d_out (32 MiB; unused until final GEMM).
    const size_t MI = 1024 * 1024;
    char* ws = (char*)d_ws;
    bf16_t* xb   = (bf16_t*)(ws);
    bf16_t* xbT  = (bf16_t*)(ws + 16 * MI);
    bf16_t* Wkb  = (bf16_t*)(ws + 32 * MI);
    bf16_t* Wvb  = (bf16_t*)(ws + 34 * MI);
    bf16_t* WqTb = (bf16_t*)(ws + 36 * MI);
    bf16_t* Gb   = (bf16_t*)(ws + 38 * MI);
    bf16_t* S1b  = (bf16_t*)(ws + 40 * MI);
    bf16_t* Ttb  = (bf16_t*)(ws + 42 * MI);
    bf16_t* Utb  = (bf16_t*)(ws + 44 * MI);
    float*  svec = (float*)(ws + 46 * MI);
    float*  kv1  = svec + 1024;
    float*  wvs  = svec + 2048;
    float*  cvec = svec + 3072;
    float*  part = out;

    dim3 blk(256);
    const float inv32 = 1.0f / 32.0f;
    const int nHH = H * H;

    // 0) prep
    hipMemsetAsync(svec, 0, H * sizeof(float), stream);
    prep_x<<<dim3(SEQ / 64, H / 64), blk, 0, stream>>>(x, xb, xbT, svec, SEQ, H);
    prep_w<<<dim3(2304), blk, 0, stream>>>(Wk, Wkb, Wv, Wvb, Wq, WqTb);

    // 1) G = x^T x  (TN=64, split-K 8 -> 1024 blocks)
    gemm_bt<128, 64, float><<<dim3(16, 8, 8), blk, 0, stream>>>(
        xbT, xbT, part, nullptr, H, H, SEQ, SEQ / 8, 1.0f, 0);
    reduce_splitk<<<dim3(nHH / 1024), blk, 0, stream>>>(part, Gb, nHH, 8, 1.0f);

    // 2) kv1 = Wk s, wvs = Wv s  (one launch)
    matvec2<<<dim3(512), blk, 0, stream>>>(Wkb, Wvb, svec, kv1, wvs, H);

    // 3) S1[j][a] = sum_b Wv[j][b] G[a][b]   (split-K 4 -> 512 blocks)
    gemm_bt<128, 64, float><<<dim3(16, 8, 4), blk, 0, stream>>>(
        Wvb, Gb, part, nullptr, H, H, H, H / 4, 1.0f, 0);
    reduce_splitk<<<dim3(nHH / 1024), blk, 0, stream>>>(part, S1b, nHH, 4, 1.0f);

    // 4) Tt[j][i] = sum_a S1[j][a] Wk[i][a] + rank-1 terms
    gemm_bt<128, 64, float><<<dim3(16, 8, 4), blk, 0, stream>>>(
        S1b, Wkb, part, nullptr, H, H, H, H / 4, 1.0f, 0);
    reduce_rank1<<<dim3(nHH / 1024), blk, 0, stream>>>(
        part, Ttb, nHH, 4, bv, kv1, wvs, bk, (float)SEQ, H);

    // 5) cvec = Tt bq /32 ;  Ut = (1/32) Tt Wq
    matvec_bf16<<<dim3(H / 4), blk, 0, stream>>>(Ttb, bq, cvec, H, inv32);
    gemm_bt<128, 64, float><<<dim3(16, 8, 4), blk, 0, stream>>>(
        Ttb, WqTb, part, nullptr, H, H, H, H / 4, 1.0f, 0);
    reduce_splitk<<<dim3(nHH / 1024), blk, 0, stream>>>(part, Utb, nHH, 4, inv32);

    // 6) out[m][j] = sum_k xb[m][k] Ut[j][k] + cvec[j]   (1024 blocks)
    gemm_bt<128, 64, float><<<dim3(16, 64), blk, 0, stream>>>(
        xb, Utb, out, cvec, SEQ, H, H, H, 1.0f, 1);
}

// Round 6
// 239.980 us; speedup vs baseline: 1.5916x; 1.0250x over previous
//
#include <hip/hip_runtime.h>
#include <hip/hip_bf16.h>
#include <stdint.h>
#include <stddef.h>

// out = x*U + 1*c^T,  U^T = Ut = (1/32)(Tt Wq),  c = (1/32) Tt bq,
// Tt = T^T, T = K^T V = Wk G Wv^T + (Wk s) bv^T + bk (Wv s)^T + N bk bv^T,
// G = x^T x (HxH, symmetric), s = colsum(x).
// Two SEQ-sized GEMMs (G, final x*Ut^T); three H^3 GEMMs run direct
// (no split-K): S1 = Wv G -> Tt = S1 Wk^T (+rank-1) -> Ut = Tt Wq /32.
typedef __bf16 bf16_t;
typedef __bf16 bf16x4 __attribute__((ext_vector_type(4)));
typedef __bf16 bf16x8 __attribute__((ext_vector_type(8)));
typedef float  floatx4 __attribute__((ext_vector_type(4)));

#define TK 32

// Fused over x [SEQ][H]: cast -> xb, transpose cast -> xbT [H][SEQ],
// column sums -> s (fp32, zeroed by prep_w). Tile 64x64, block 256.
__global__ void prep_x(const float* __restrict__ x, bf16_t* __restrict__ xb,
                       bf16_t* __restrict__ xbT, float* __restrict__ s,
                       int SEQ, int H) {
    __shared__ bf16_t tile[64][72];
    __shared__ float csum[64];
    const int t = threadIdx.x;
    const int n0 = blockIdx.x * 64, k0 = blockIdx.y * 64;
    const int c4 = t & 15;
    const int rbase = t >> 4;
    float a0 = 0.f, a1 = 0.f, a2 = 0.f, a3 = 0.f;
    if (t < 64) csum[t] = 0.f;
    #pragma unroll
    for (int p = 0; p < 4; ++p) {
        const int r = rbase + 16 * p;
        const size_t gidx = (size_t)(n0 + r) * H + k0 + c4 * 4;
        float4 f = *(const float4*)(x + gidx);
        bf16x4 o;
        o.x = (bf16_t)f.x; o.y = (bf16_t)f.y;
        o.z = (bf16_t)f.z; o.w = (bf16_t)f.w;
        *(bf16x4*)(xb + gidx) = o;
        *(bf16x4*)&tile[r][c4 * 4] = o;
        a0 += f.x; a1 += f.y; a2 += f.z; a3 += f.w;
    }
    __syncthreads();
    atomicAdd(&csum[c4 * 4 + 0], a0);
    atomicAdd(&csum[c4 * 4 + 1], a1);
    atomicAdd(&csum[c4 * 4 + 2], a2);
    atomicAdd(&csum[c4 * 4 + 3], a3);
    #pragma unroll
    for (int p = 0; p < 2; ++p) {
        const int q = t + 256 * p;
        const int kk = q >> 3;
        const int n8 = (q & 7) * 8;
        bf16x8 v;
        #pragma unroll
        for (int u = 0; u < 8; ++u) v[u] = tile[n8 + u][kk];
        *(bf16x8*)(xbT + (size_t)(k0 + kk) * SEQ + n0 + n8) = v;
    }
    __syncthreads();
    if (t < 64) atomicAdd(s + k0 + t, csum[t]);
}

// Weight prep + svec zero: blocks [0,1024) cast Wk, [1024,2048) cast Wv,
// [2048,2304) transpose-cast Wq (64x64 tiles), block 2304 zeroes svec.
__global__ void prep_w(const float* __restrict__ Wk, bf16_t* __restrict__ Wkb,
                       const float* __restrict__ Wv, bf16_t* __restrict__ Wvb,
                       const float* __restrict__ Wq, bf16_t* __restrict__ WqTb,
                       float* __restrict__ svec) {
    __shared__ bf16_t tile[64][72];
    const int b = blockIdx.x;
    const int t = threadIdx.x;
    if (b == 2304) {
        *(float4*)(svec + t * 4) = float4{0.f, 0.f, 0.f, 0.f};
        return;
    }
    if (b < 2048) {
        const float* s = (b < 1024) ? Wk : Wv;
        bf16_t* d = (b < 1024) ? Wkb : Wvb;
        const int base = (b & 1023) * 1024 + t * 4;
        float4 f = *(const float4*)(s + base);
        bf16x4 o;
        o.x = (bf16_t)f.x; o.y = (bf16_t)f.y;
        o.z = (bf16_t)f.z; o.w = (bf16_t)f.w;
        *(bf16x4*)(d + base) = o;
    } else {
        const int bb = b - 2048;
        const int r0 = (bb & 15) * 64, c0 = (bb >> 4) * 64;
        const int c4 = t & 15;
        const int rbase = t >> 4;
        #pragma unroll
        for (int p = 0; p < 4; ++p) {
            const int r = rbase + 16 * p;
            float4 f = *(const float4*)(Wq + (size_t)(r0 + r) * 1024 + c0 + c4 * 4);
            bf16x4 o;
            o.x = (bf16_t)f.x; o.y = (bf16_t)f.y;
            o.z = (bf16_t)f.z; o.w = (bf16_t)f.w;
            *(bf16x4*)&tile[r][c4 * 4] = o;
        }
        __syncthreads();
        #pragma unroll
        for (int p = 0; p < 2; ++p) {
            const int q = t + 256 * p;
            const int cc = q >> 3;
            const int r8 = (q & 7) * 8;
            bf16x8 v;
            #pragma unroll
            for (int u = 0; u < 8; ++u) v[u] = tile[r8 + u][cc];
            *(bf16x8*)(WqTb + (size_t)(c0 + cc) * 1024 + r0 + r8) = v;
        }
    }
}

// Two matvecs: y0 = M0 v (rows 0..1023), y1 = M1 v. Wave/row, grid 512.
__global__ void matvec2(const bf16_t* __restrict__ M0,
                        const bf16_t* __restrict__ M1,
                        const float* __restrict__ v,
                        float* __restrict__ y0, float* __restrict__ y1,
                        int ncols) {
    const int lane = threadIdx.x & 63;
    const int row = blockIdx.x * 4 + (threadIdx.x >> 6);
    const bf16_t* mp;
    float* y;
    if (row < 1024) { mp = M0 + (size_t)row * ncols;          y = y0 + row; }
    else            { mp = M1 + (size_t)(row - 1024) * ncols; y = y1 + row - 1024; }
    float acc = 0.f;
    for (int a = lane * 8; a < ncols; a += 512) {
        bf16x8 m8 = *(const bf16x8*)(mp + a);
        #pragma unroll
        for (int u = 0; u < 8; ++u) acc += (float)m8[u] * v[a + u];
    }
    #pragma unroll
    for (int off = 32; off; off >>= 1) acc += __shfl_down(acc, off);
    if (lane == 0) *y = acc;
}

// y[row] = scale * sum_a M[row][a] * v[a].  Wave/row, grid rows/4.
__global__ void matvec_bf16(const bf16_t* __restrict__ M,
                            const float* __restrict__ v,
                            float* __restrict__ y, int ncols, float scale) {
    const int lane = threadIdx.x & 63;
    const int row = blockIdx.x * 4 + (threadIdx.x >> 6);
    const bf16_t* mp = M + (size_t)row * ncols;
    float acc = 0.f;
    for (int a = lane * 8; a < ncols; a += 512) {
        bf16x8 m8 = *(const bf16x8*)(mp + a);
        #pragma unroll
        for (int u = 0; u < 8; ++u) acc += (float)m8[u] * v[a + u];
    }
    #pragma unroll
    for (int off = 32; off; off >>= 1) acc += __shfl_down(acc, off);
    if (lane == 0) y[row] = acc * scale;
}

// Sum nsplit fp32 partial slabs of n elems, scale, cast to bf16.
__global__ void reduce_splitk(const float* __restrict__ part,
                              bf16_t* __restrict__ dst, int n, int nsplit,
                              float scale) {
    int i = (blockIdx.x * blockDim.x + threadIdx.x) * 4;
    if (i < n) {
        float4 ssum = *(const float4*)(part + i);
        for (int z = 1; z < nsplit; ++z) {
            float4 p = *(const float4*)(part + (size_t)z * n + i);
            ssum.x += p.x; ssum.y += p.y; ssum.z += p.z; ssum.w += p.w;
        }
        bf16x4 o;
        o.x = (bf16_t)(ssum.x * scale); o.y = (bf16_t)(ssum.y * scale);
        o.z = (bf16_t)(ssum.z * scale); o.w = (bf16_t)(ssum.w * scale);
        *(bf16x4*)(dst + i) = o;
    }
}

// C[z][M,N] = scale*(A[M, k0:k0+kChunk] @ B[N, k0:k0+kChunk]^T) + epilogue.
// MODE 0: none. MODE 1: +p1[col]. MODE 2 (rank-1):
//   +p1[row]*p2[col] + p3[row]*p4[col] + cN*p1[row]*p4[col].
// Tile TMp x TNp, 4 waves (2x2); 16x16x32 bf16 MFMA; global_load_lds
// width-16 into unpadded row-major LDS tiles. z = blockIdx.z.
template <int TMp, int TNp, int MODE, typename OutT>
__global__ __launch_bounds__(256, 2) void gemm_bt(
    const bf16_t* __restrict__ A,
    const bf16_t* __restrict__ B,
    OutT* __restrict__ C,
    const float* __restrict__ p1, const float* __restrict__ p2,
    const float* __restrict__ p3, const float* __restrict__ p4,
    int M, int N, int K, int kChunk, float scale, float cN)
{
    __shared__ __align__(16) bf16_t As[TMp * TK];
    __shared__ __align__(16) bf16_t Bs[TNp * TK];
    constexpr int MF = TMp / 32;
    constexpr int NF = TNp / 32;
    constexpr int nA = TMp / 64;
    constexpr int nB = TNp / 64;

    const int tid  = threadIdx.x;
    const int lane = tid & 63;
    const int wave = tid >> 6;
    const int wm   = wave >> 1;
    const int wn   = wave & 1;

    const int bm = blockIdx.y * TMp;
    const int bn = blockIdx.x * TNp;
    const int k0 = blockIdx.z * kChunk;
    C += (size_t)blockIdx.z * M * N;

    floatx4 acc[MF][NF] = {};

    const int fr = lane & 15;
    const int fk = (lane >> 4) * 8;

    for (int kt = k0; kt < k0 + kChunk; kt += TK) {
        #pragma unroll
        for (int p = 0; p < nA; ++p) {
            const int c = tid + 256 * p;
            const int r = c >> 2, o = (c & 3) * 8;
            __builtin_amdgcn_global_load_lds(
                (const __attribute__((address_space(1))) void*)
                    (A + (size_t)(bm + r) * K + kt + o),
                (__attribute__((address_space(3))) void*)&As[c * 8], 16, 0, 0);
        }
        #pragma unroll
        for (int p = 0; p < nB; ++p) {
            const int c = tid + 256 * p;
            const int r = c >> 2, o = (c & 3) * 8;
            __builtin_amdgcn_global_load_lds(
                (const __attribute__((address_space(1))) void*)
                    (B + (size_t)(bn + r) * K + kt + o),
                (__attribute__((address_space(3))) void*)&Bs[c * 8], 16, 0, 0);
        }
        __syncthreads();

        bf16x8 af[MF], bg[NF];
        #pragma unroll
        for (int i = 0; i < MF; ++i)
            af[i] = *(const bf16x8*)&As[(wm * (TMp / 2) + i * 16 + fr) * TK + fk];
        #pragma unroll
        for (int j = 0; j < NF; ++j)
            bg[j] = *(const bf16x8*)&Bs[(wn * (TNp / 2) + j * 16 + fr) * TK + fk];
        #pragma unroll
        for (int i = 0; i < MF; ++i) {
            #pragma unroll
            for (int j = 0; j < NF; ++j) {
                acc[i][j] = __builtin_amdgcn_mfma_f32_16x16x32_bf16(
                    af[i], bg[j], acc[i][j], 0, 0, 0);
            }
        }
        __syncthreads();
    }

    // C/D layout (verified): col = lane&15, row = (lane>>4)*4 + reg.
    const int rq = (lane >> 4) * 4;
    #pragma unroll
    for (int i = 0; i < MF; ++i) {
        #pragma unroll
        for (int j = 0; j < NF; ++j) {
            const int col = bn + wn * (TNp / 2) + j * 16 + fr;
            #pragma unroll
            for (int r = 0; r < 4; ++r) {
                const int row = bm + wm * (TMp / 2) + i * 16 + rq + r;
                float v = acc[i][j][r] * scale;
                if (MODE == 1) v += p1[col];
                if (MODE == 2) v += p1[row] * p2[col] + p3[row] * p4[col]
                                  + cN * p1[row] * p4[col];
                C[(size_t)row * N + col] = (OutT)v;
            }
        }
    }
}

extern "C" void kernel_launch(void* const* d_in, const int* in_sizes, int n_in,
                              void* d_out, int out_size, void* d_ws, size_t ws_size,
                              hipStream_t stream) {
    const int SEQ = 8192;
    const int H   = 1024;

    const float* x  = (const float*)d_in[0];
    const float* Wq = (const float*)d_in[1];
    const float* bq = (const float*)d_in[2];
    const float* Wk = (const float*)d_in[3];
    const float* bk = (const float*)d_in[4];
    const float* Wv = (const float*)d_in[5];
    const float* bv = (const float*)d_in[6];
    float* out = (float*)d_out;

    // Workspace: [0,16)Mi xb  [16,32)Mi xbT  [32,34)Mi Wkb  [34,36)Mi Wvb
    // [36,38)Mi WqTb  [38,40)Mi Gb  [40,42)Mi S1b  [42,44)Mi Ttb
    // [44,46)Mi Utb   46Mi+: svec,kv1,wvs,cvec (fp32 H each)
    // G split-8 fp32 partials (32 MiB) live in d_out until the final GEMM.
    const size_t MI = 1024 * 1024;
    char* ws = (char*)d_ws;
    bf16_t* xb   = (bf16_t*)(ws);
    bf16_t* xbT  = (bf16_t*)(ws + 16 * MI);
    bf16_t* Wkb  = (bf16_t*)(ws + 32 * MI);
    bf16_t* Wvb  = (bf16_t*)(ws + 34 * MI);
    bf16_t* WqTb = (bf16_t*)(ws + 36 * MI);
    bf16_t* Gb   = (bf16_t*)(ws + 38 * MI);
    bf16_t* S1b  = (bf16_t*)(ws + 40 * MI);
    bf16_t* Ttb  = (bf16_t*)(ws + 42 * MI);
    bf16_t* Utb  = (bf16_t*)(ws + 44 * MI);
    float*  svec = (float*)(ws + 46 * MI);
    float*  kv1  = svec + 1024;
    float*  wvs  = svec + 2048;
    float*  cvec = svec + 3072;
    float*  part = out;

    dim3 blk(256);
    const float inv32 = 1.0f / 32.0f;
    const int nHH = H * H;
    const float* nil = nullptr;

    // 1) weights cast/transpose + svec zero
    prep_w<<<dim3(2305), blk, 0, stream>>>(Wk, Wkb, Wv, Wvb, Wq, WqTb, svec);
    // 2) x cast/transpose/colsum
    prep_x<<<dim3(SEQ / 64, H / 64), blk, 0, stream>>>(x, xb, xbT, svec, SEQ, H);
    // 3) kv1 = Wk s, wvs = Wv s
    matvec2<<<dim3(512), blk, 0, stream>>>(Wkb, Wvb, svec, kv1, wvs, H);
    // 4) G = x^T x   (64x64 tiles, split-K 8 -> 2048 blocks, 8/CU)
    gemm_bt<64, 64, 0, float><<<dim3(16, 16, 8), blk, 0, stream>>>(
        xbT, xbT, part, nil, nil, nil, nil, H, H, SEQ, SEQ / 8, 1.0f, 0.f);
    // 5) Gb = sum_z part
    reduce_splitk<<<dim3(nHH / 1024), blk, 0, stream>>>(part, Gb, nHH, 8, 1.0f);
    // 6) S1 = Wv G   (direct, 256 blocks, K=1024)
    gemm_bt<64, 64, 0, bf16_t><<<dim3(16, 16), blk, 0, stream>>>(
        Wvb, Gb, S1b, nil, nil, nil, nil, H, H, H, H, 1.0f, 0.f);
    // 7) Tt = S1 Wk^T + bv kv1^T + wvs bk^T + N bv bk^T   (direct)
    gemm_bt<64, 64, 2, bf16_t><<<dim3(16, 16), blk, 0, stream>>>(
        S1b, Wkb, Ttb, bv, kv1, wvs, bk, H, H, H, H, 1.0f, (float)SEQ);
    // 8) cvec = (1/32) Tt bq
    matvec_bf16<<<dim3(H / 4), blk, 0, stream>>>(Ttb, bq, cvec, H, inv32);
    // 9) Ut = (1/32) Tt Wq   (direct)
    gemm_bt<64, 64, 0, bf16_t><<<dim3(16, 16), blk, 0, stream>>>(
        Ttb, WqTb, Utb, nil, nil, nil, nil, H, H, H, H, inv32, 0.f);
    // 10) out = xb Ut^T + cvec  (fp32, 1024 blocks)
    gemm_bt<128, 64, 1, float><<<dim3(16, 64), blk, 0, stream>>>(
        xb, Utb, out, cvec, nil, nil, nil, SEQ, H, H, H, 1.0f, 0.f);
}

// Round 7
// 232.432 us; speedup vs baseline: 1.6433x; 1.0325x over previous
//
#include <hip/hip_runtime.h>
#include <hip/hip_bf16.h>
#include <stdint.h>
#include <stddef.h>

// out = x*U + 1*c^T,  U^T = Ut = (1/32)(Tt Wq),  c = (1/32) Tt bq,
// Tt = T^T, T = K^T V = Wk G Wv^T + (Wk s) bv^T + bk (Wv s)^T + N bk bv^T,
// G = x^T x (HxH, symmetric), s = colsum(x).
// Two SEQ-sized GEMMs (G, final x*Ut^T); three H^3 GEMMs run direct.
typedef __bf16 bf16_t;
typedef __bf16 bf16x4 __attribute__((ext_vector_type(4)));
typedef __bf16 bf16x8 __attribute__((ext_vector_type(8)));
typedef float  floatx4 __attribute__((ext_vector_type(4)));

#define TK 32

// Fused over x [SEQ][H]: cast -> xb, transpose cast -> xbT [H][SEQ],
// column sums -> s (fp32, zeroed by prep_w). Tile 64x64, block 256.
__global__ void prep_x(const float* __restrict__ x, bf16_t* __restrict__ xb,
                       bf16_t* __restrict__ xbT, float* __restrict__ s,
                       int SEQ, int H) {
    __shared__ bf16_t tile[64][72];
    __shared__ float csum[64];
    const int t = threadIdx.x;
    const int n0 = blockIdx.x * 64, k0 = blockIdx.y * 64;
    const int c4 = t & 15;
    const int rbase = t >> 4;
    float a0 = 0.f, a1 = 0.f, a2 = 0.f, a3 = 0.f;
    if (t < 64) csum[t] = 0.f;
    #pragma unroll
    for (int p = 0; p < 4; ++p) {
        const int r = rbase + 16 * p;
        const size_t gidx = (size_t)(n0 + r) * H + k0 + c4 * 4;
        float4 f = *(const float4*)(x + gidx);
        bf16x4 o;
        o.x = (bf16_t)f.x; o.y = (bf16_t)f.y;
        o.z = (bf16_t)f.z; o.w = (bf16_t)f.w;
        *(bf16x4*)(xb + gidx) = o;
        *(bf16x4*)&tile[r][c4 * 4] = o;
        a0 += f.x; a1 += f.y; a2 += f.z; a3 += f.w;
    }
    __syncthreads();
    atomicAdd(&csum[c4 * 4 + 0], a0);
    atomicAdd(&csum[c4 * 4 + 1], a1);
    atomicAdd(&csum[c4 * 4 + 2], a2);
    atomicAdd(&csum[c4 * 4 + 3], a3);
    #pragma unroll
    for (int p = 0; p < 2; ++p) {
        const int q = t + 256 * p;
        const int kk = q >> 3;
        const int n8 = (q & 7) * 8;
        bf16x8 v;
        #pragma unroll
        for (int u = 0; u < 8; ++u) v[u] = tile[n8 + u][kk];
        *(bf16x8*)(xbT + (size_t)(k0 + kk) * SEQ + n0 + n8) = v;
    }
    __syncthreads();
    if (t < 64) atomicAdd(s + k0 + t, csum[t]);
}

// Weight prep + svec zero: blocks [0,1024) cast Wk, [1024,2048) cast Wv,
// [2048,2304) transpose-cast Wq (64x64 tiles), block 2304 zeroes svec.
__global__ void prep_w(const float* __restrict__ Wk, bf16_t* __restrict__ Wkb,
                       const float* __restrict__ Wv, bf16_t* __restrict__ Wvb,
                       const float* __restrict__ Wq, bf16_t* __restrict__ WqTb,
                       float* __restrict__ svec) {
    __shared__ bf16_t tile[64][72];
    const int b = blockIdx.x;
    const int t = threadIdx.x;
    if (b == 2304) {
        *(float4*)(svec + t * 4) = float4{0.f, 0.f, 0.f, 0.f};
        return;
    }
    if (b < 2048) {
        const float* s = (b < 1024) ? Wk : Wv;
        bf16_t* d = (b < 1024) ? Wkb : Wvb;
        const int base = (b & 1023) * 1024 + t * 4;
        float4 f = *(const float4*)(s + base);
        bf16x4 o;
        o.x = (bf16_t)f.x; o.y = (bf16_t)f.y;
        o.z = (bf16_t)f.z; o.w = (bf16_t)f.w;
        *(bf16x4*)(d + base) = o;
    } else {
        const int bb = b - 2048;
        const int r0 = (bb & 15) * 64, c0 = (bb >> 4) * 64;
        const int c4 = t & 15;
        const int rbase = t >> 4;
        #pragma unroll
        for (int p = 0; p < 4; ++p) {
            const int r = rbase + 16 * p;
            float4 f = *(const float4*)(Wq + (size_t)(r0 + r) * 1024 + c0 + c4 * 4);
            bf16x4 o;
            o.x = (bf16_t)f.x; o.y = (bf16_t)f.y;
            o.z = (bf16_t)f.z; o.w = (bf16_t)f.w;
            *(bf16x4*)&tile[r][c4 * 4] = o;
        }
        __syncthreads();
        #pragma unroll
        for (int p = 0; p < 2; ++p) {
            const int q = t + 256 * p;
            const int cc = q >> 3;
            const int r8 = (q & 7) * 8;
            bf16x8 v;
            #pragma unroll
            for (int u = 0; u < 8; ++u) v[u] = tile[r8 + u][cc];
            *(bf16x8*)(WqTb + (size_t)(c0 + cc) * 1024 + r0 + r8) = v;
        }
    }
}

// Two matvecs: y0 = M0 v (rows 0..1023), y1 = M1 v. Wave/row, grid 512.
__global__ void matvec2(const bf16_t* __restrict__ M0,
                        const bf16_t* __restrict__ M1,
                        const float* __restrict__ v,
                        float* __restrict__ y0, float* __restrict__ y1,
                        int ncols) {
    const int lane = threadIdx.x & 63;
    const int row = blockIdx.x * 4 + (threadIdx.x >> 6);
    const bf16_t* mp;
    float* y;
    if (row < 1024) { mp = M0 + (size_t)row * ncols;          y = y0 + row; }
    else            { mp = M1 + (size_t)(row - 1024) * ncols; y = y1 + row - 1024; }
    float acc = 0.f;
    for (int a = lane * 8; a < ncols; a += 512) {
        bf16x8 m8 = *(const bf16x8*)(mp + a);
        #pragma unroll
        for (int u = 0; u < 8; ++u) acc += (float)m8[u] * v[a + u];
    }
    #pragma unroll
    for (int off = 32; off; off >>= 1) acc += __shfl_down(acc, off);
    if (lane == 0) *y = acc;
}

// y[row] = scale * sum_a M[row][a] * v[a].  Wave/row, grid rows/4.
__global__ void matvec_bf16(const bf16_t* __restrict__ M,
                            const float* __restrict__ v,
                            float* __restrict__ y, int ncols, float scale) {
    const int lane = threadIdx.x & 63;
    const int row = blockIdx.x * 4 + (threadIdx.x >> 6);
    const bf16_t* mp = M + (size_t)row * ncols;
    float acc = 0.f;
    for (int a = lane * 8; a < ncols; a += 512) {
        bf16x8 m8 = *(const bf16x8*)(mp + a);
        #pragma unroll
        for (int u = 0; u < 8; ++u) acc += (float)m8[u] * v[a + u];
    }
    #pragma unroll
    for (int off = 32; off; off >>= 1) acc += __shfl_down(acc, off);
    if (lane == 0) y[row] = acc * scale;
}

// Sum nsplit fp32 partial slabs of n elems, scale, cast to bf16.
__global__ void reduce_splitk(const float* __restrict__ part,
                              bf16_t* __restrict__ dst, int n, int nsplit,
                              float scale) {
    int i = (blockIdx.x * blockDim.x + threadIdx.x) * 4;
    if (i < n) {
        float4 ssum = *(const float4*)(part + i);
        for (int z = 1; z < nsplit; ++z) {
            float4 p = *(const float4*)(part + (size_t)z * n + i);
            ssum.x += p.x; ssum.y += p.y; ssum.z += p.z; ssum.w += p.w;
        }
        bf16x4 o;
        o.x = (bf16_t)(ssum.x * scale); o.y = (bf16_t)(ssum.y * scale);
        o.z = (bf16_t)(ssum.z * scale); o.w = (bf16_t)(ssum.w * scale);
        *(bf16x4*)(dst + i) = o;
    }
}

// C[z][M,N] = scale*(A[M, k0:k0+kChunk] @ B[N, k0:k0+kChunk]^T) + epilogue.
// MODE 0: none. MODE 1: +p1[col]. MODE 2 (rank-1):
//   +p1[row]*p2[col] + p3[row]*p4[col] + cN*p1[row]*p4[col].
// Tile TMp x TNp, 4 waves (2x2); 16x16x32 bf16 MFMA; global_load_lds
// width-16 into unpadded row-major LDS tiles. z = blockIdx.z.
template <int TMp, int TNp, int MODE, typename OutT>
__global__ __launch_bounds__(256, 2) void gemm_bt(
    const bf16_t* __restrict__ A,
    const bf16_t* __restrict__ B,
    OutT* __restrict__ C,
    const float* __restrict__ p1, const float* __restrict__ p2,
    const float* __restrict__ p3, const float* __restrict__ p4,
    int M, int N, int K, int kChunk, float scale, float cN)
{
    __shared__ __align__(16) bf16_t As[TMp * TK];
    __shared__ __align__(16) bf16_t Bs[TNp * TK];
    constexpr int MF = TMp / 32;
    constexpr int NF = TNp / 32;
    constexpr int nA = TMp / 64;
    constexpr int nB = TNp / 64;

    const int tid  = threadIdx.x;
    const int lane = tid & 63;
    const int wave = tid >> 6;
    const int wm   = wave >> 1;
    const int wn   = wave & 1;

    const int bm = blockIdx.y * TMp;
    const int bn = blockIdx.x * TNp;
    const int k0 = blockIdx.z * kChunk;
    C += (size_t)blockIdx.z * M * N;

    floatx4 acc[MF][NF] = {};

    const int fr = lane & 15;
    const int fk = (lane >> 4) * 8;

    for (int kt = k0; kt < k0 + kChunk; kt += TK) {
        #pragma unroll
        for (int p = 0; p < nA; ++p) {
            const int c = tid + 256 * p;
            const int r = c >> 2, o = (c & 3) * 8;
            __builtin_amdgcn_global_load_lds(
                (const __attribute__((address_space(1))) void*)
                    (A + (size_t)(bm + r) * K + kt + o),
                (__attribute__((address_space(3))) void*)&As[c * 8], 16, 0, 0);
        }
        #pragma unroll
        for (int p = 0; p < nB; ++p) {
            const int c = tid + 256 * p;
            const int r = c >> 2, o = (c & 3) * 8;
            __builtin_amdgcn_global_load_lds(
                (const __attribute__((address_space(1))) void*)
                    (B + (size_t)(bn + r) * K + kt + o),
                (__attribute__((address_space(3))) void*)&Bs[c * 8], 16, 0, 0);
        }
        __syncthreads();

        bf16x8 af[MF], bg[NF];
        #pragma unroll
        for (int i = 0; i < MF; ++i)
            af[i] = *(const bf16x8*)&As[(wm * (TMp / 2) + i * 16 + fr) * TK + fk];
        #pragma unroll
        for (int j = 0; j < NF; ++j)
            bg[j] = *(const bf16x8*)&Bs[(wn * (TNp / 2) + j * 16 + fr) * TK + fk];
        #pragma unroll
        for (int i = 0; i < MF; ++i) {
            #pragma unroll
            for (int j = 0; j < NF; ++j) {
                acc[i][j] = __builtin_amdgcn_mfma_f32_16x16x32_bf16(
                    af[i], bg[j], acc[i][j], 0, 0, 0);
            }
        }
        __syncthreads();
    }

    // C/D layout (verified): col = lane&15, row = (lane>>4)*4 + reg.
    const int rq = (lane >> 4) * 4;
    #pragma unroll
    for (int i = 0; i < MF; ++i) {
        #pragma unroll
        for (int j = 0; j < NF; ++j) {
            const int col = bn + wn * (TNp / 2) + j * 16 + fr;
            #pragma unroll
            for (int r = 0; r < 4; ++r) {
                const int row = bm + wm * (TMp / 2) + i * 16 + rq + r;
                float v = acc[i][j][r] * scale;
                if (MODE == 1) v += p1[col];
                if (MODE == 2) v += p1[row] * p2[col] + p3[row] * p4[col]
                                  + cN * p1[row] * p4[col];
                C[(size_t)row * N + col] = (OutT)v;
            }
        }
    }
}

extern "C" void kernel_launch(void* const* d_in, const int* in_sizes, int n_in,
                              void* d_out, int out_size, void* d_ws, size_t ws_size,
                              hipStream_t stream) {
    const int SEQ = 8192;
    const int H   = 1024;

    const float* x  = (const float*)d_in[0];
    const float* Wq = (const float*)d_in[1];
    const float* bq = (const float*)d_in[2];
    const float* Wk = (const float*)d_in[3];
    const float* bk = (const float*)d_in[4];
    const float* Wv = (const float*)d_in[5];
    const float* bv = (const float*)d_in[6];
    float* out = (float*)d_out;

    // Workspace: [0,16)Mi xb  [16,32)Mi xbT  [32,34)Mi Wkb  [34,36)Mi Wvb
    // [36,38)Mi WqTb  [38,40)Mi Gb  [40,42)Mi S1b  [42,44)Mi Ttb
    // [44,46)Mi Utb   46Mi+: svec,kv1,wvs,cvec (fp32 H each)
    // [48,112)Mi: G split-16 fp32 partials (16 x 4 MiB).
    const size_t MI = 1024 * 1024;
    char* ws = (char*)d_ws;
    bf16_t* xb   = (bf16_t*)(ws);
    bf16_t* xbT  = (bf16_t*)(ws + 16 * MI);
    bf16_t* Wkb  = (bf16_t*)(ws + 32 * MI);
    bf16_t* Wvb  = (bf16_t*)(ws + 34 * MI);
    bf16_t* WqTb = (bf16_t*)(ws + 36 * MI);
    bf16_t* Gb   = (bf16_t*)(ws + 38 * MI);
    bf16_t* S1b  = (bf16_t*)(ws + 40 * MI);
    bf16_t* Ttb  = (bf16_t*)(ws + 42 * MI);
    bf16_t* Utb  = (bf16_t*)(ws + 44 * MI);
    float*  svec = (float*)(ws + 46 * MI);
    float*  kv1  = svec + 1024;
    float*  wvs  = svec + 2048;
    float*  cvec = svec + 3072;
    float*  part = (float*)(ws + 48 * MI);

    dim3 blk(256);
    const float inv32 = 1.0f / 32.0f;
    const int nHH = H * H;
    const float* nil = nullptr;

    // 1) weights cast/transpose + svec zero
    prep_w<<<dim3(2305), blk, 0, stream>>>(Wk, Wkb, Wv, Wvb, Wq, WqTb, svec);
    // 2) x cast/transpose/colsum
    prep_x<<<dim3(SEQ / 64, H / 64), blk, 0, stream>>>(x, xb, xbT, svec, SEQ, H);
    // 3) kv1 = Wk s, wvs = Wv s
    matvec2<<<dim3(512), blk, 0, stream>>>(Wkb, Wvb, svec, kv1, wvs, H);
    // 4) G = x^T x   (128x128 tiles: 16 MFMA/wave/iter; split-K 16 ->
    //    1024 blocks = 4/CU. Density AND occupancy together.)
    gemm_bt<128, 128, 0, float><<<dim3(8, 8, 16), blk, 0, stream>>>(
        xbT, xbT, part, nil, nil, nil, nil, H, H, SEQ, SEQ / 16, 1.0f, 0.f);
    // 5) Gb = sum_z part
    reduce_splitk<<<dim3(nHH / 1024), blk, 0, stream>>>(part, Gb, nHH, 16, 1.0f);
    // 6) S1 = Wv G   (direct, 256 blocks, K=1024)
    gemm_bt<64, 64, 0, bf16_t><<<dim3(16, 16), blk, 0, stream>>>(
        Wvb, Gb, S1b, nil, nil, nil, nil, H, H, H, H, 1.0f, 0.f);
    // 7) Tt = S1 Wk^T + bv kv1^T + wvs bk^T + N bv bk^T   (direct)
    gemm_bt<64, 64, 2, bf16_t><<<dim3(16, 16), blk, 0, stream>>>(
        S1b, Wkb, Ttb, bv, kv1, wvs, bk, H, H, H, H, 1.0f, (float)SEQ);
    // 8) cvec = (1/32) Tt bq
    matvec_bf16<<<dim3(H / 4), blk, 0, stream>>>(Ttb, bq, cvec, H, inv32);
    // 9) Ut = (1/32) Tt Wq   (direct)
    gemm_bt<64, 64, 0, bf16_t><<<dim3(16, 16), blk, 0, stream>>>(
        Ttb, WqTb, Utb, nil, nil, nil, nil, H, H, H, H, inv32, 0.f);
    // 10) out = xb Ut^T + cvec  (fp32, 512 blocks)
    gemm_bt<128, 128, 1, float><<<dim3(8, 64), blk, 0, stream>>>(
        xb, Utb, out, cvec, nil, nil, nil, SEQ, H, H, H, 1.0f, 0.f);
}

// Round 8
// 230.935 us; speedup vs baseline: 1.6540x; 1.0065x over previous
//
#include <hip/hip_runtime.h>
#include <hip/hip_bf16.h>
#include <stdint.h>
#include <stddef.h>

// out = x*U + 1*c^T,  Ut = U^T = (1/32)(Tt Wq),  c = (1/32) Tt bq,
// Tt = T^T, T = K^T V = Wk G Wv^T + (Wk s) bv^T + bk (Wv s)^T + N bk bv^T,
// G = x^T x (HxH, symmetric), s = colsum(x).
// Staging model (r3/r6/r7): global->LDS feed is concurrency+latency limited
// (~6/8.5/11 TB/s at 2/4/8 blk/CU). So: big tiles (fewer bytes), split-K
// (more blocks), XCD-swizzle (L2-pin per-XCD working sets <= 4 MB).
typedef __bf16 bf16_t;
typedef __bf16 bf16x4 __attribute__((ext_vector_type(4)));
typedef __bf16 bf16x8 __attribute__((ext_vector_type(8)));
typedef float  floatx4 __attribute__((ext_vector_type(4)));

#define TK 32

// Fused over x [SEQ][H]: cast -> xb, transpose cast -> xbT [H][SEQ],
// column sums -> s (fp32, zeroed by prep_w). Tile 64x64, block 256.
__global__ void prep_x(const float* __restrict__ x, bf16_t* __restrict__ xb,
                       bf16_t* __restrict__ xbT, float* __restrict__ s,
                       int SEQ, int H) {
    __shared__ bf16_t tile[64][72];
    __shared__ float csum[64];
    const int t = threadIdx.x;
    const int n0 = blockIdx.x * 64, k0 = blockIdx.y * 64;
    const int c4 = t & 15;
    const int rbase = t >> 4;
    float a0 = 0.f, a1 = 0.f, a2 = 0.f, a3 = 0.f;
    if (t < 64) csum[t] = 0.f;
    #pragma unroll
    for (int p = 0; p < 4; ++p) {
        const int r = rbase + 16 * p;
        const size_t gidx = (size_t)(n0 + r) * H + k0 + c4 * 4;
        float4 f = *(const float4*)(x + gidx);
        bf16x4 o;
        o.x = (bf16_t)f.x; o.y = (bf16_t)f.y;
        o.z = (bf16_t)f.z; o.w = (bf16_t)f.w;
        *(bf16x4*)(xb + gidx) = o;
        *(bf16x4*)&tile[r][c4 * 4] = o;
        a0 += f.x; a1 += f.y; a2 += f.z; a3 += f.w;
    }
    __syncthreads();
    atomicAdd(&csum[c4 * 4 + 0], a0);
    atomicAdd(&csum[c4 * 4 + 1], a1);
    atomicAdd(&csum[c4 * 4 + 2], a2);
    atomicAdd(&csum[c4 * 4 + 3], a3);
    #pragma unroll
    for (int p = 0; p < 2; ++p) {
        const int q = t + 256 * p;
        const int kk = q >> 3;
        const int n8 = (q & 7) * 8;
        bf16x8 v;
        #pragma unroll
        for (int u = 0; u < 8; ++u) v[u] = tile[n8 + u][kk];
        *(bf16x8*)(xbT + (size_t)(k0 + kk) * SEQ + n0 + n8) = v;
    }
    __syncthreads();
    if (t < 64) atomicAdd(s + k0 + t, csum[t]);
}

// Weight prep + svec zero: blocks [0,1024) cast Wk, [1024,2048) cast Wv,
// [2048,2304) transpose-cast Wq (64x64 tiles), block 2304 zeroes svec.
__global__ void prep_w(const float* __restrict__ Wk, bf16_t* __restrict__ Wkb,
                       const float* __restrict__ Wv, bf16_t* __restrict__ Wvb,
                       const float* __restrict__ Wq, bf16_t* __restrict__ WqTb,
                       float* __restrict__ svec) {
    __shared__ bf16_t tile[64][72];
    const int b = blockIdx.x;
    const int t = threadIdx.x;
    if (b == 2304) {
        *(float4*)(svec + t * 4) = float4{0.f, 0.f, 0.f, 0.f};
        return;
    }
    if (b < 2048) {
        const float* s = (b < 1024) ? Wk : Wv;
        bf16_t* d = (b < 1024) ? Wkb : Wvb;
        const int base = (b & 1023) * 1024 + t * 4;
        float4 f = *(const float4*)(s + base);
        bf16x4 o;
        o.x = (bf16_t)f.x; o.y = (bf16_t)f.y;
        o.z = (bf16_t)f.z; o.w = (bf16_t)f.w;
        *(bf16x4*)(d + base) = o;
    } else {
        const int bb = b - 2048;
        const int r0 = (bb & 15) * 64, c0 = (bb >> 4) * 64;
        const int c4 = t & 15;
        const int rbase = t >> 4;
        #pragma unroll
        for (int p = 0; p < 4; ++p) {
            const int r = rbase + 16 * p;
            float4 f = *(const float4*)(Wq + (size_t)(r0 + r) * 1024 + c0 + c4 * 4);
            bf16x4 o;
            o.x = (bf16_t)f.x; o.y = (bf16_t)f.y;
            o.z = (bf16_t)f.z; o.w = (bf16_t)f.w;
            *(bf16x4*)&tile[r][c4 * 4] = o;
        }
        __syncthreads();
        #pragma unroll
        for (int p = 0; p < 2; ++p) {
            const int q = t + 256 * p;
            const int cc = q >> 3;
            const int r8 = (q & 7) * 8;
            bf16x8 v;
            #pragma unroll
            for (int u = 0; u < 8; ++u) v[u] = tile[r8 + u][cc];
            *(bf16x8*)(WqTb + (size_t)(c0 + cc) * 1024 + r0 + r8) = v;
        }
    }
}

// Two matvecs: y0 = M0 v (rows 0..1023), y1 = M1 v. Wave/row, grid 512.
__global__ void matvec2(const bf16_t* __restrict__ M0,
                        const bf16_t* __restrict__ M1,
                        const float* __restrict__ v,
                        float* __restrict__ y0, float* __restrict__ y1,
                        int ncols) {
    const int lane = threadIdx.x & 63;
    const int row = blockIdx.x * 4 + (threadIdx.x >> 6);
    const bf16_t* mp;
    float* y;
    if (row < 1024) { mp = M0 + (size_t)row * ncols;          y = y0 + row; }
    else            { mp = M1 + (size_t)(row - 1024) * ncols; y = y1 + row - 1024; }
    float acc = 0.f;
    for (int a = lane * 8; a < ncols; a += 512) {
        bf16x8 m8 = *(const bf16x8*)(mp + a);
        #pragma unroll
        for (int u = 0; u < 8; ++u) acc += (float)m8[u] * v[a + u];
    }
    #pragma unroll
    for (int off = 32; off; off >>= 1) acc += __shfl_down(acc, off);
    if (lane == 0) *y = acc;
}

// y[row] = scale * sum_a M[row][a] * v[a].  Wave/row, grid rows/4.
__global__ void matvec_bf16(const bf16_t* __restrict__ M,
                            const float* __restrict__ v,
                            float* __restrict__ y, int ncols, float scale) {
    const int lane = threadIdx.x & 63;
    const int row = blockIdx.x * 4 + (threadIdx.x >> 6);
    const bf16_t* mp = M + (size_t)row * ncols;
    float acc = 0.f;
    for (int a = lane * 8; a < ncols; a += 512) {
        bf16x8 m8 = *(const bf16x8*)(mp + a);
        #pragma unroll
        for (int u = 0; u < 8; ++u) acc += (float)m8[u] * v[a + u];
    }
    #pragma unroll
    for (int off = 32; off; off >>= 1) acc += __shfl_down(acc, off);
    if (lane == 0) y[row] = acc * scale;
}

// Sum nsplit bf16 partial slabs of n elems (8 per thread), scale -> bf16.
__global__ void reduce_bf16(const bf16_t* __restrict__ part,
                            bf16_t* __restrict__ dst, int n, int nsplit,
                            float scale) {
    int i = (blockIdx.x * blockDim.x + threadIdx.x) * 8;
    if (i < n) {
        float acc[8] = {};
        for (int z = 0; z < nsplit; ++z) {
            bf16x8 p = *(const bf16x8*)(part + (size_t)z * n + i);
            #pragma unroll
            for (int u = 0; u < 8; ++u) acc[u] += (float)p[u];
        }
        bf16x8 o;
        #pragma unroll
        for (int u = 0; u < 8; ++u) o[u] = (bf16_t)(acc[u] * scale);
        *(bf16x8*)(dst + i) = o;
    }
}

// Same, plus rank-1 bias terms for Tt:
//   dst[j][i] = sum_z part + bv[j]*kv1[i] + wvs[j]*bk[i] + cN*bv[j]*bk[i]
__global__ void reduce_bf16_rank1(const bf16_t* __restrict__ part,
                                  bf16_t* __restrict__ dst, int n, int nsplit,
                                  const float* __restrict__ bv,
                                  const float* __restrict__ kv1,
                                  const float* __restrict__ wvs,
                                  const float* __restrict__ bk,
                                  float cN, int Hdim) {
    int i = (blockIdx.x * blockDim.x + threadIdx.x) * 8;
    if (i < n) {
        float acc[8] = {};
        for (int z = 0; z < nsplit; ++z) {
            bf16x8 p = *(const bf16x8*)(part + (size_t)z * n + i);
            #pragma unroll
            for (int u = 0; u < 8; ++u) acc[u] += (float)p[u];
        }
        const int j = i / Hdim, ii = i % Hdim;
        const float bvj = bv[j], wvsj = wvs[j];
        bf16x8 o;
        #pragma unroll
        for (int u = 0; u < 8; ++u) {
            float v = acc[u] + bvj * kv1[ii + u] + (wvsj + cN * bvj) * bk[ii + u];
            o[u] = (bf16_t)v;
        }
        *(bf16x8*)(dst + i) = o;
    }
}

// C[z][M,N] = scale*(A[M, k0:k0+kChunk] @ B[N, k0:k0+kChunk]^T) + epilogue.
// MODE 0: none. MODE 1: +p1[col].
// SWZ (XCD-aware block swizzle; XCD = linear_block_id % 8 heuristic):
//  0: standard 2-D/3-D grid (bx=n, by=m, bz=z)
//  1: grid 1024 1-D (G): z = 2*(L&7)+(L>>9), mn=(L>>3)&63  -> 2 z/XCD
//  2: grid 512 1-D (final): m_tile = 8*(L&7)+((L>>3)&7), n = L>>6
//  3: grid 512 1-D (H^3 split-8): z = L&7, mn = L>>3
// Tile TMp x TNp, 4 waves (2x2); 16x16x32 bf16 MFMA; global_load_lds
// width-16 into unpadded row-major LDS tiles.
template <int TMp, int TNp, int MODE, int SWZ, typename OutT>
__global__ __launch_bounds__(256, 2) void gemm_bt(
    const bf16_t* __restrict__ A,
    const bf16_t* __restrict__ B,
    OutT* __restrict__ C,
    const float* __restrict__ p1,
    int M, int N, int K, int kChunk, float scale)
{
    __shared__ __align__(16) bf16_t As[TMp * TK];
    __shared__ __align__(16) bf16_t Bs[TNp * TK];
    constexpr int MF = TMp / 32;
    constexpr int NF = TNp / 32;
    constexpr int nA = TMp / 64;
    constexpr int nB = TNp / 64;

    const int tid  = threadIdx.x;
    const int lane = tid & 63;
    const int wave = tid >> 6;
    const int wm   = wave >> 1;
    const int wn   = wave & 1;

    int bm, bn, z;
    if (SWZ == 0) {
        bm = blockIdx.y * TMp; bn = blockIdx.x * TNp; z = blockIdx.z;
    } else if (SWZ == 1) {
        const int L = blockIdx.x;
        z = ((L & 7) << 1) | (L >> 9);
        const int mn = (L >> 3) & 63;
        bm = (mn >> 3) * TMp; bn = (mn & 7) * TNp;
    } else if (SWZ == 2) {
        const int L = blockIdx.x;
        bm = ((L & 7) * 8 + ((L >> 3) & 7)) * TMp;
        bn = (L >> 6) * TNp;
        z = 0;
    } else {
        const int L = blockIdx.x;
        z = L & 7;
        const int mn = L >> 3;
        bm = (mn >> 3) * TMp; bn = (mn & 7) * TNp;
    }
    const int k0 = z * kChunk;
    C += (size_t)z * M * N;

    floatx4 acc[MF][NF] = {};

    const int fr = lane & 15;
    const int fk = (lane >> 4) * 8;

    for (int kt = k0; kt < k0 + kChunk; kt += TK) {
        #pragma unroll
        for (int p = 0; p < nA; ++p) {
            const int c = tid + 256 * p;
            const int r = c >> 2, o = (c & 3) * 8;
            __builtin_amdgcn_global_load_lds(
                (const __attribute__((address_space(1))) void*)
                    (A + (size_t)(bm + r) * K + kt + o),
                (__attribute__((address_space(3))) void*)&As[c * 8], 16, 0, 0);
        }
        #pragma unroll
        for (int p = 0; p < nB; ++p) {
            const int c = tid + 256 * p;
            const int r = c >> 2, o = (c & 3) * 8;
            __builtin_amdgcn_global_load_lds(
                (const __attribute__((address_space(1))) void*)
                    (B + (size_t)(bn + r) * K + kt + o),
                (__attribute__((address_space(3))) void*)&Bs[c * 8], 16, 0, 0);
        }
        __syncthreads();

        bf16x8 af[MF], bg[NF];
        #pragma unroll
        for (int i = 0; i < MF; ++i)
            af[i] = *(const bf16x8*)&As[(wm * (TMp / 2) + i * 16 + fr) * TK + fk];
        #pragma unroll
        for (int j = 0; j < NF; ++j)
            bg[j] = *(const bf16x8*)&Bs[(wn * (TNp / 2) + j * 16 + fr) * TK + fk];
        #pragma unroll
        for (int i = 0; i < MF; ++i) {
            #pragma unroll
            for (int j = 0; j < NF; ++j) {
                acc[i][j] = __builtin_amdgcn_mfma_f32_16x16x32_bf16(
                    af[i], bg[j], acc[i][j], 0, 0, 0);
            }
        }
        __syncthreads();
    }

    // C/D layout (verified): col = lane&15, row = (lane>>4)*4 + reg.
    const int rq = (lane >> 4) * 4;
    #pragma unroll
    for (int i = 0; i < MF; ++i) {
        #pragma unroll
        for (int j = 0; j < NF; ++j) {
            const int col = bn + wn * (TNp / 2) + j * 16 + fr;
            #pragma unroll
            for (int r = 0; r < 4; ++r) {
                const int row = bm + wm * (TMp / 2) + i * 16 + rq + r;
                float v = acc[i][j][r] * scale;
                if (MODE == 1) v += p1[col];
                C[(size_t)row * N + col] = (OutT)v;
            }
        }
    }
}

extern "C" void kernel_launch(void* const* d_in, const int* in_sizes, int n_in,
                              void* d_out, int out_size, void* d_ws, size_t ws_size,
                              hipStream_t stream) {
    const int SEQ = 8192;
    const int H   = 1024;

    const float* x  = (const float*)d_in[0];
    const float* Wq = (const float*)d_in[1];
    const float* bq = (const float*)d_in[2];
    const float* Wk = (const float*)d_in[3];
    const float* bk = (const float*)d_in[4];
    const float* Wv = (const float*)d_in[5];
    const float* bv = (const float*)d_in[6];
    float* out = (float*)d_out;

    // Workspace: [0,16)Mi xb  [16,32)Mi xbT  [32,34)Mi Wkb  [34,36)Mi Wvb
    // [36,38)Mi WqTb  [38,40)Mi Gb  [40,42)Mi S1b  [42,44)Mi Ttb
    // [44,46)Mi Utb   46Mi+: svec,kv1,wvs,cvec (fp32 H each)
    // [48,80)Mi: bf16 split-K partials (max 16 x 2 MiB).
    const size_t MI = 1024 * 1024;
    char* ws = (char*)d_ws;
    bf16_t* xb   = (bf16_t*)(ws);
    bf16_t* xbT  = (bf16_t*)(ws + 16 * MI);
    bf16_t* Wkb  = (bf16_t*)(ws + 32 * MI);
    bf16_t* Wvb  = (bf16_t*)(ws + 34 * MI);
    bf16_t* WqTb = (bf16_t*)(ws + 36 * MI);
    bf16_t* Gb   = (bf16_t*)(ws + 38 * MI);
    bf16_t* S1b  = (bf16_t*)(ws + 40 * MI);
    bf16_t* Ttb  = (bf16_t*)(ws + 42 * MI);
    bf16_t* Utb  = (bf16_t*)(ws + 44 * MI);
    float*  svec = (float*)(ws + 46 * MI);
    float*  kv1  = svec + 1024;
    float*  wvs  = svec + 2048;
    float*  cvec = svec + 3072;
    bf16_t* part = (bf16_t*)(ws + 48 * MI);

    dim3 blk(256);
    const float inv32 = 1.0f / 32.0f;
    const int nHH = H * H;
    const int rgrid = nHH / 8 / 256;   // 512 blocks for the reduces
    const float* nil = nullptr;

    // 1) weights cast/transpose + svec zero
    prep_w<<<dim3(2305), blk, 0, stream>>>(Wk, Wkb, Wv, Wvb, Wq, WqTb, svec);
    // 2) x cast/transpose/colsum
    prep_x<<<dim3(SEQ / 64, H / 64), blk, 0, stream>>>(x, xb, xbT, svec, SEQ, H);
    // 3) kv1 = Wk s, wvs = Wv s
    matvec2<<<dim3(512), blk, 0, stream>>>(Wkb, Wvb, svec, kv1, wvs, H);
    // 4) G = x^T x   (128^2, split-16, XCD-swizzled: 2 z-slices per XCD)
    gemm_bt<128, 128, 0, 1, bf16_t><<<dim3(1024), blk, 0, stream>>>(
        xbT, xbT, part, nil, H, H, SEQ, SEQ / 16, 1.0f);
    reduce_bf16<<<dim3(rgrid), blk, 0, stream>>>(part, Gb, nHH, 16, 1.0f);
    // 5) S1 = Wv G   (128^2, split-8, swizzled)
    gemm_bt<128, 128, 0, 3, bf16_t><<<dim3(512), blk, 0, stream>>>(
        Wvb, Gb, part, nil, H, H, H, H / 8, 1.0f);
    reduce_bf16<<<dim3(rgrid), blk, 0, stream>>>(part, S1b, nHH, 8, 1.0f);
    // 6) Tt = S1 Wk^T + bv kv1^T + wvs bk^T + N bv bk^T
    gemm_bt<128, 128, 0, 3, bf16_t><<<dim3(512), blk, 0, stream>>>(
        S1b, Wkb, part, nil, H, H, H, H / 8, 1.0f);
    reduce_bf16_rank1<<<dim3(rgrid), blk, 0, stream>>>(
        part, Ttb, nHH, 8, bv, kv1, wvs, bk, (float)SEQ, H);
    // 7) cvec = (1/32) Tt bq
    matvec_bf16<<<dim3(H / 4), blk, 0, stream>>>(Ttb, bq, cvec, H, inv32);
    // 8) Ut = (1/32) Tt Wq
    gemm_bt<128, 128, 0, 3, bf16_t><<<dim3(512), blk, 0, stream>>>(
        Ttb, WqTb, part, nil, H, H, H, H / 8, 1.0f);
    reduce_bf16<<<dim3(rgrid), blk, 0, stream>>>(part, Utb, nHH, 8, inv32);
    // 9) out = xb Ut^T + cvec  (fp32; XCD-swizzled: 8 m-tiles + full B / XCD)
    gemm_bt<128, 128, 1, 2, float><<<dim3(512), blk, 0, stream>>>(
        xb, Utb, out, cvec, SEQ, H, H, H, 1.0f);
}